// Round 3
// baseline (1005.004 us; speedup 1.0000x reference)
//
#include <hip/hip_runtime.h>
#include <hip/hip_bf16.h>
#include <math.h>

// Problem constants
#define TT 4
#define VV 4096
#define EE 4096
#define KK 32
#define DD 8
#define HH 16
#define BERTD 768
#define CATD 784
#define NH 196     // CAT/4 hidden units of EdgeConv MLP
#define NTOT 260   // 196 hidden + 64 pe (Wih_m projection)
#define KPAD 800   // K padded to 25*32
#define NPAD 272   // N padded to 17*16
#define LDT 40     // LDS row stride in halves (80B, 16B-aligned)

typedef __bf16 bf16x8 __attribute__((ext_vector_type(8)));
typedef float  f32x4  __attribute__((ext_vector_type(4)));

__device__ __forceinline__ float sigmoidf_(float x){ return 1.0f/(1.0f+expf(-x)); }
__device__ __forceinline__ float dot4_(float4 a, float4 b){
  return fmaf(a.x,b.x, fmaf(a.y,b.y, fmaf(a.z,b.z, a.w*b.w)));
}
__device__ __forceinline__ unsigned short f2bf(float f){
  __bf16 h = (__bf16)f;
  return __builtin_bit_cast(unsigned short, h);
}

// ---------------------------------------------------------------------------
// K1: price LSTM. (T,V,1) -> new_prices (T,V,16). 16 lanes per vertex.
// ---------------------------------------------------------------------------
__global__ __launch_bounds__(256) void k1_price_lstm(
    const float* __restrict__ prices,
    const float* __restrict__ Wih, const float* __restrict__ Whh,
    const float* __restrict__ bih, const float* __restrict__ bhh,
    float* __restrict__ np_out){
  int tid  = threadIdx.x;
  int lane = tid & 15;
  int v    = (blockIdx.x*256 + tid) >> 4;
  float W[4][16], wih[4], b[4];
#pragma unroll
  for (int gi=0; gi<4; ++gi){
    int j = gi*16 + lane;
    const float4* wr = reinterpret_cast<const float4*>(&Whh[j*16]);
    float4 w0=wr[0], w1=wr[1], w2=wr[2], w3=wr[3];
    W[gi][0]=w0.x; W[gi][1]=w0.y; W[gi][2]=w0.z; W[gi][3]=w0.w;
    W[gi][4]=w1.x; W[gi][5]=w1.y; W[gi][6]=w1.z; W[gi][7]=w1.w;
    W[gi][8]=w2.x; W[gi][9]=w2.y; W[gi][10]=w2.z; W[gi][11]=w2.w;
    W[gi][12]=w3.x; W[gi][13]=w3.y; W[gi][14]=w3.z; W[gi][15]=w3.w;
    wih[gi] = Wih[j];
    b[gi]   = bih[j] + bhh[j];
  }
  float h = 0.f, c = 0.f;
  for (int t=0; t<TT; ++t){
    float x = prices[t*VV + v];
    float a0 = fmaf(x, wih[0], b[0]);
    float a1 = fmaf(x, wih[1], b[1]);
    float a2 = fmaf(x, wih[2], b[2]);
    float a3 = fmaf(x, wih[3], b[3]);
#pragma unroll
    for (int d=0; d<16; ++d){
      float hb = __shfl(h, d, 16);
      a0 = fmaf(hb, W[0][d], a0);
      a1 = fmaf(hb, W[1][d], a1);
      a2 = fmaf(hb, W[2][d], a2);
      a3 = fmaf(hb, W[3][d], a3);
    }
    float ig = sigmoidf_(a0);
    float fg = sigmoidf_(a1);
    float gg = tanhf(a2);
    float og = sigmoidf_(a3);
    c = fmaf(fg, c, ig*gg);
    h = og * tanhf(c);
    np_out[(size_t)(t*VV+v)*16 + lane] = h;
  }
}

// ---------------------------------------------------------------------------
// K2a: per (te-tile, k): scores = reg_k . tw[k]^T + tb[k]; softmax over j;
// wsum[te][j] += cw[k] * softmax_j. Grid (TE/64, 32), 256 thr.
// Wave jq handles j in [jq*8, jq*8+8) for all 64 te of the tile.
// ---------------------------------------------------------------------------
__global__ __launch_bounds__(256) void k2a_mult(
    const float* __restrict__ np, const int* __restrict__ mem,
    const float* __restrict__ tw, const float* __restrict__ tb,
    const float* __restrict__ cw, float* __restrict__ wsum){
  int k   = blockIdx.y;
  int tid = threadIdx.x;
  int lane = tid & 63;
  int jq   = tid >> 6;
  int te   = blockIdx.x*64 + lane;
  int t    = te >> 12;
  __shared__ float stw[32*20];
  __shared__ float stb[32];
  __shared__ float rmax[4][64];
  __shared__ float rsum[4][64];
  for (int i = tid; i < 512; i += 256)
    stw[(i >> 4)*20 + (i & 15)] = tw[(size_t)k*512 + i];
  if (tid < 32) stb[tid] = tb[k*32 + tid];
  __syncthreads();
  int vid = mem[(size_t)te*32 + k];
  const float4* rp = reinterpret_cast<const float4*>(&np[((size_t)(t*VV) + vid)*16]);
  float4 r0 = rp[0], r1 = rp[1], r2 = rp[2], r3 = rp[3];
  float sc[8]; float mx = -1e30f;
#pragma unroll
  for (int jj = 0; jj < 8; ++jj){
    int j = jq*8 + jj;
    const float4* w4 = reinterpret_cast<const float4*>(&stw[j*20]);
    float a = stb[j] + dot4_(r0,w4[0]) + dot4_(r1,w4[1]) + dot4_(r2,w4[2]) + dot4_(r3,w4[3]);
    sc[jj] = a; mx = fmaxf(mx, a);
  }
  float sm = 0.f;
#pragma unroll
  for (int jj = 0; jj < 8; ++jj){ sc[jj] = expf(sc[jj] - mx); sm += sc[jj]; }
  rmax[jq][lane] = mx; rsum[jq][lane] = sm;
  __syncthreads();
  float m0 = rmax[0][lane], m1 = rmax[1][lane], m2 = rmax[2][lane], m3 = rmax[3][lane];
  float gmx = fmaxf(fmaxf(m0,m1), fmaxf(m2,m3));
  float gsm = rsum[0][lane]*expf(m0-gmx) + rsum[1][lane]*expf(m1-gmx)
            + rsum[2][lane]*expf(m2-gmx) + rsum[3][lane]*expf(m3-gmx);
  float f = expf(mx - gmx) * cw[k] / gsm;
  float* wp = &wsum[(size_t)te*32 + jq*8];
#pragma unroll
  for (int jj = 0; jj < 8; ++jj) atomicAdd(&wp[jj], sc[jj] * f);
}

// ---------------------------------------------------------------------------
// K2b: he_emb[te][d] = cb + sum_j wsum[te][j] * np[t, mem[te][j], d]
// One wave per te (4 per block). lane: d = l&15, j-group = l>>4.
// ---------------------------------------------------------------------------
__global__ __launch_bounds__(256) void k2b_heemb(
    const float* __restrict__ np, const int* __restrict__ mem,
    const float* __restrict__ wsum, const float* __restrict__ cb,
    float* __restrict__ he_emb){
  int tid = threadIdx.x;
  int te = blockIdx.x*4 + (tid >> 6);
  int l = tid & 63;
  int t = te >> 12;
  int d = l & 15, jg = l >> 4;
  float acc = 0.f;
#pragma unroll
  for (int jj = 0; jj < 8; ++jj){
    int j = jg*8 + jj;
    int vid = mem[(size_t)te*32 + j];
    float wv = wsum[(size_t)te*32 + j];
    acc = fmaf(wv, np[((size_t)(t*VV) + vid)*16 + d], acc);
  }
  acc += __shfl_xor(acc, 16);
  acc += __shfl_xor(acc, 32);
  if (l < 16) he_emb[(size_t)te*16 + d] = acc + cb[0];
}

// ---------------------------------------------------------------------------
// K3pre: pack [ec_w1 ; Wih_m] into bf16 Bbf[NPAD][KPAD], zero-padded.
// ---------------------------------------------------------------------------
__global__ __launch_bounds__(256) void k3pre(
    const float* __restrict__ w1, const float* __restrict__ wm,
    unsigned short* __restrict__ Bbf){
  int n = blockIdx.x;
  const float* src = nullptr;
  if (n < NH) src = &w1[(size_t)n*CATD];
  else if (n < NTOT) src = &wm[(size_t)(n-NH)*CATD];
  for (int kx = threadIdx.x; kx < KPAD; kx += 256){
    float v = (src != nullptr && kx < CATD) ? src[kx] : 0.f;
    Bbf[(size_t)n*KPAD + kx] = f2bf(v);
  }
}

// ---------------------------------------------------------------------------
// K3: bf16 MFMA GEMM, M-tile 32, full N=272 in one pass, BK=32 x 25 steps.
// A = [he_emb | node] converted inline to bf16. 8 waves (512 thr):
// wave w: row-frag r=w&1, col-group c=w>>2? -> c=w>>1: frags fb..fb+nf-1.
// Epilogue: hidden cols -> relu*w2 partial, atomicAdd esc[m]; pe cols -> C_pe.
// ---------------------------------------------------------------------------
__global__ __launch_bounds__(512) void k3_gemm_mfma(
    const float* __restrict__ he_emb, const float* __restrict__ node,
    const unsigned short* __restrict__ Bbf, const float* __restrict__ b1,
    const float* __restrict__ w2, float* __restrict__ esc,
    float* __restrict__ C_pe){
  __shared__ __bf16 As[32*LDT];
  __shared__ __bf16 Bs[NPAD*LDT];
  int tid = threadIdx.x;
  int m0 = blockIdx.x * 32;
  int l = tid & 63;
  int w = tid >> 6;
  int r = w & 1;
  int c = w >> 1;                       // 0..3
  int fb = (c == 0) ? 0 : (1 + 4*c);    // 0,5,9,13
  int nf = (c == 0) ? 5 : 4;
  f32x4 acc[5] = {};
  int arow = tid >> 3;                  // (threads<256) 0..31
  int akq  = (tid & 7) * 4;
  unsigned short* AsU = reinterpret_cast<unsigned short*>(As);
  unsigned short* BsU = reinterpret_cast<unsigned short*>(Bs);
  for (int step = 0; step < 25; ++step){
    int ks = step * 32;
    if (tid < 256){
      int m = m0 + arow;
      int k = ks + akq;
      float4 av = make_float4(0.f,0.f,0.f,0.f);
      if (k < 16)        av = *reinterpret_cast<const float4*>(&he_emb[(size_t)m*16 + k]);
      else if (k < CATD) av = *reinterpret_cast<const float4*>(&node[(size_t)m*BERTD + (k-16)]);
      ushort4 uv;
      uv.x = f2bf(av.x); uv.y = f2bf(av.y); uv.z = f2bf(av.z); uv.w = f2bf(av.w);
      *reinterpret_cast<ushort4*>(&AsU[arow*LDT + akq]) = uv;
    }
    for (int i = tid; i < (NPAD*32/4); i += 512){
      int n = i >> 3, kk = (i & 7) * 4;
      ushort4 uv = *reinterpret_cast<const ushort4*>(&Bbf[(size_t)n*KPAD + ks + kk]);
      *reinterpret_cast<ushort4*>(&BsU[n*LDT + kk]) = uv;
    }
    __syncthreads();
    bf16x8 af = *reinterpret_cast<const bf16x8*>(&As[(r*16 + (l & 15))*LDT + (l >> 4)*8]);
#pragma unroll
    for (int f = 0; f < 5; ++f){
      if (f < nf){
        int n16 = (fb + f) * 16;
        bf16x8 bfr = *reinterpret_cast<const bf16x8*>(&Bs[(n16 + (l & 15))*LDT + (l >> 4)*8]);
        acc[f] = __builtin_amdgcn_mfma_f32_16x16x32_bf16(af, bfr, acc[f], 0, 0, 0);
      }
    }
    __syncthreads();
  }
  // epilogue
  float p[4] = {0.f,0.f,0.f,0.f};
#pragma unroll
  for (int f = 0; f < 5; ++f){
    if (f < nf){
      int n = (fb + f)*16 + (l & 15);
      float b1n = (n < NH) ? b1[n] : 0.f;
      float w2n = (n < NH) ? w2[n] : 0.f;
#pragma unroll
      for (int i = 0; i < 4; ++i){
        float v = acc[f][i];
        if (n < NH){
          p[i] += fmaxf(v + b1n, 0.f) * w2n;
        } else if (n < NTOT){
          int m = m0 + r*16 + (l >> 4)*4 + i;
          C_pe[(size_t)m*64 + (n - NH)] = v;
        }
      }
    }
  }
#pragma unroll
  for (int i = 0; i < 4; ++i){
#pragma unroll
    for (int off = 1; off < 16; off <<= 1) p[i] += __shfl_xor(p[i], off, 16);
    if ((l & 15) == 0){
      int m = m0 + r*16 + (l >> 4)*4 + i;
      atomicAdd(&esc[m], p[i]);
    }
  }
}

// ---------------------------------------------------------------------------
// K4: per (t,v): softmax over D=8 edge scores (b2 cancels), blend C_pe rows
// -> g_in (T,V,64). One wave per (t,v).
// ---------------------------------------------------------------------------
__global__ __launch_bounds__(256) void k4_edge_gather(
    const int* __restrict__ ve, const float* __restrict__ esc,
    const float* __restrict__ C_pe, float* __restrict__ g_in){
  int tid = threadIdx.x;
  int lane = tid & 63;
  int tv = blockIdx.x*4 + (tid >> 6);
  int t = tv >> 12;
  const int* vp = &ve[(size_t)tv*8];
  int e[8]; float w[8];
  float mx = -1e30f;
#pragma unroll
  for (int d = 0; d < 8; ++d){
    e[d] = vp[d];
    w[d] = esc[(t << 12) + e[d]];
    mx = fmaxf(mx, w[d]);
  }
  float s = 0.f;
#pragma unroll
  for (int d = 0; d < 8; ++d){ w[d] = expf(w[d]-mx); s += w[d]; }
  float inv = 1.f/s;
  float a = 0.f;
#pragma unroll
  for (int d = 0; d < 8; ++d)
    a = fmaf(w[d], C_pe[(size_t)((t << 12) + e[d])*64 + lane], a);
  g_in[(size_t)tv*64 + lane] = a * inv;
}

// ---------------------------------------------------------------------------
// K5: second LSTM (input pre-projected in g_in) + residual. 16 lanes/vertex.
// ---------------------------------------------------------------------------
__global__ __launch_bounds__(256) void k5_lstm2(
    const float* __restrict__ g_in, const float* __restrict__ Whh,
    const float* __restrict__ bih, const float* __restrict__ bhh,
    const float* __restrict__ np, float* __restrict__ la){
  int tid  = threadIdx.x;
  int lane = tid & 15;
  int v    = (blockIdx.x*256 + tid) >> 4;
  float W[4][16], b[4];
#pragma unroll
  for (int gi=0; gi<4; ++gi){
    int j = gi*16 + lane;
    const float4* wr = reinterpret_cast<const float4*>(&Whh[j*16]);
    float4 w0=wr[0], w1=wr[1], w2=wr[2], w3=wr[3];
    W[gi][0]=w0.x; W[gi][1]=w0.y; W[gi][2]=w0.z; W[gi][3]=w0.w;
    W[gi][4]=w1.x; W[gi][5]=w1.y; W[gi][6]=w1.z; W[gi][7]=w1.w;
    W[gi][8]=w2.x; W[gi][9]=w2.y; W[gi][10]=w2.z; W[gi][11]=w2.w;
    W[gi][12]=w3.x; W[gi][13]=w3.y; W[gi][14]=w3.z; W[gi][15]=w3.w;
    b[gi] = bih[j] + bhh[j];
  }
  float h = 0.f, c = 0.f;
  for (int t=0; t<TT; ++t){
    const float* gi_p = &g_in[(size_t)(t*VV+v)*64];
    float a0 = gi_p[lane]      + b[0];
    float a1 = gi_p[16 + lane] + b[1];
    float a2 = gi_p[32 + lane] + b[2];
    float a3 = gi_p[48 + lane] + b[3];
#pragma unroll
    for (int d=0; d<16; ++d){
      float hb = __shfl(h, d, 16);
      a0 = fmaf(hb, W[0][d], a0);
      a1 = fmaf(hb, W[1][d], a1);
      a2 = fmaf(hb, W[2][d], a2);
      a3 = fmaf(hb, W[3][d], a3);
    }
    float ig = sigmoidf_(a0);
    float fg = sigmoidf_(a1);
    float gg = tanhf(a2);
    float og = sigmoidf_(a3);
    c = fmaf(fg, c, ig*gg);
    h = og * tanhf(c);
    la[(size_t)(t*VV+v)*16 + lane] = h + np[(size_t)(t*VV+v)*16 + lane];
  }
}

// ---------------------------------------------------------------------------
// K6: attention + tanh proj + FC. 16 lanes per vertex.
// ---------------------------------------------------------------------------
__global__ __launch_bounds__(256) void k6_attn_fc(
    const float* __restrict__ la, const float* __restrict__ ain,
    const float* __restrict__ aout, const float* __restrict__ fcw,
    const float* __restrict__ fcb, float* __restrict__ out){
  __shared__ float s_ain[16*17];
  __shared__ float s_aout[16*33];
  __shared__ float s_fc[32];
  __shared__ float s_fcb[2];
  int tid = threadIdx.x;
  { int j = tid >> 4, d = tid & 15; s_ain[j*17+d] = ain[tid]; }
  for (int i = tid; i < 512; i += 256){ int j = i >> 5, d = i & 31; s_aout[j*33+d] = aout[i]; }
  if (tid < 32) s_fc[tid] = fcw[tid];
  if (tid < 2)  s_fcb[tid] = fcb[tid];
  __syncthreads();
  int lane = tid & 15;
  int v = (blockIdx.x*256 + tid) >> 4;
  float l0 = la[(size_t)(0*VV+v)*16 + lane];
  float l1 = la[(size_t)(1*VV+v)*16 + lane];
  float l2 = la[(size_t)(2*VV+v)*16 + lane];
  float l3 = la[(size_t)(3*VV+v)*16 + lane];
  float q = 0.f;
#pragma unroll
  for (int d=0; d<16; ++d){
    float bb = __shfl(l3, d, 16);
    q = fmaf(bb, s_ain[lane*17+d], q);
  }
  float aw0 = q*l0, aw1 = q*l1, aw2 = q*l2, aw3 = q*l3;
#pragma unroll
  for (int off=1; off<16; off<<=1){
    aw0 += __shfl_xor(aw0, off, 16);
    aw1 += __shfl_xor(aw1, off, 16);
    aw2 += __shfl_xor(aw2, off, 16);
    aw3 += __shfl_xor(aw3, off, 16);
  }
  float mx = fmaxf(fmaxf(aw0,aw1), fmaxf(aw2,aw3));
  aw0 = expf(aw0-mx); aw1 = expf(aw1-mx); aw2 = expf(aw2-mx); aw3 = expf(aw3-mx);
  float inv = 1.f/(aw0+aw1+aw2+aw3);
  float mix = (aw0*l0 + aw1*l1 + aw2*l2 + aw3*l3) * inv;
  float a = 0.f;
#pragma unroll
  for (int d=0; d<16; ++d){
    float m  = __shfl(mix, d, 16);
    float qq = __shfl(q,  d, 16);
    a = fmaf(m,  s_aout[lane*33+d],    a);
    a = fmaf(qq, s_aout[lane*33+16+d], a);
  }
  float at = tanhf(a);
  float p0 = at * s_fc[lane];
  float p1 = at * s_fc[16+lane];
#pragma unroll
  for (int off=1; off<16; off<<=1){
    p0 += __shfl_xor(p0, off, 16);
    p1 += __shfl_xor(p1, off, 16);
  }
  if (lane == 0){
    out[(size_t)v*2 + 0] = p0 + s_fcb[0];
    out[(size_t)v*2 + 1] = p1 + s_fcb[1];
  }
}

// ---------------------------------------------------------------------------
extern "C" void kernel_launch(void* const* d_in, const int* in_sizes, int n_in,
                              void* d_out, int out_size, void* d_ws, size_t ws_size,
                              hipStream_t stream){
  const float* prices = (const float*)d_in[0];
  const float* node   = (const float*)d_in[1];
  const int*   mem    = (const int*)d_in[2];
  const int*   ve     = (const int*)d_in[3];
  const float* Wih_p  = (const float*)d_in[4];
  const float* Whh_p  = (const float*)d_in[5];
  const float* bih_p  = (const float*)d_in[6];
  const float* bhh_p  = (const float*)d_in[7];
  const float* Wih_m  = (const float*)d_in[8];
  const float* Whh_m  = (const float*)d_in[9];
  const float* bih_m  = (const float*)d_in[10];
  const float* bhh_m  = (const float*)d_in[11];
  const float* tw     = (const float*)d_in[12];
  const float* tb     = (const float*)d_in[13];
  const float* cw     = (const float*)d_in[14];
  const float* cb     = (const float*)d_in[15];
  const float* w1     = (const float*)d_in[16];
  const float* b1     = (const float*)d_in[17];
  const float* w2     = (const float*)d_in[18];
  // d_in[19] = ec_b2: cancels in softmax, unused
  const float* ain    = (const float*)d_in[20];
  const float* aout   = (const float*)d_in[21];
  const float* fcw    = (const float*)d_in[22];
  const float* fcb    = (const float*)d_in[23];

  // workspace layout (floats)
  float* np_buf = (float*)d_ws;                       // T*V*16      = 262144
  float* he_emb = np_buf + (size_t)TT*VV*HH;          // T*E*16      = 262144
  float* wsum   = he_emb + (size_t)TT*EE*HH;          // T*E*32      = 524288
  float* esc    = wsum   + (size_t)TT*EE*32;          // T*E         = 16384
  float* C_pe   = esc    + (size_t)TT*EE;             // 16384*64    = 1048576
  float* g_in   = C_pe   + (size_t)TT*EE*64;          // T*V*64      = 1048576
  float* la_buf = g_in   + (size_t)TT*VV*64;          // T*V*16      = 262144
  unsigned short* Bbf = (unsigned short*)(la_buf + (size_t)TT*VV*HH); // 272*800 u16

  hipMemsetAsync(wsum, 0, (size_t)TT*EE*32*sizeof(float), stream);
  hipMemsetAsync(esc,  0, (size_t)TT*EE*sizeof(float), stream);

  k1_price_lstm<<<(VV*16)/256, 256, 0, stream>>>(prices, Wih_p, Whh_p, bih_p, bhh_p, np_buf);
  k3pre<<<NPAD, 256, 0, stream>>>(w1, Wih_m, Bbf);
  k2a_mult<<<dim3((TT*EE)/64, KK), 256, 0, stream>>>(np_buf, mem, tw, tb, cw, wsum);
  k2b_heemb<<<(TT*EE)/4, 256, 0, stream>>>(np_buf, mem, wsum, cb, he_emb);
  k3_gemm_mfma<<<(TT*EE)/32, 512, 0, stream>>>(he_emb, node, Bbf, b1, w2, esc, C_pe);
  k4_edge_gather<<<(TT*VV)/4, 256, 0, stream>>>(ve, esc, C_pe, g_in);
  k5_lstm2<<<(VV*16)/256, 256, 0, stream>>>(g_in, Whh_m, bih_m, bhh_m, np_buf, la_buf);
  k6_attn_fc<<<(VV*16)/256, 256, 0, stream>>>(la_buf, ain, aout, fcw, fcb, (float*)d_out);
}

// Round 4
// 264.410 us; speedup vs baseline: 3.8009x; 3.8009x over previous
//
#include <hip/hip_runtime.h>
#include <hip/hip_bf16.h>
#include <math.h>

// Problem constants
#define TT 4
#define VV 4096
#define EE 4096
#define KK 32
#define DD 8
#define HH 16
#define BERTD 768
#define CATD 784
#define NH 196     // CAT/4 hidden units of EdgeConv MLP
#define NTOT 260   // 196 hidden + 64 pe (Wih_m projection)
#define KPAD 800   // K padded to 25*32
#define NPAD 272   // N padded to 17*16
#define LDT 40     // LDS row stride in halves (80B, 16B-aligned)

typedef __bf16 bf16x8 __attribute__((ext_vector_type(8)));
typedef float  f32x4  __attribute__((ext_vector_type(4)));

__device__ __forceinline__ float sigmoidf_(float x){ return 1.0f/(1.0f+expf(-x)); }
__device__ __forceinline__ float dot4_(float4 a, float4 b){
  return fmaf(a.x,b.x, fmaf(a.y,b.y, fmaf(a.z,b.z, a.w*b.w)));
}
__device__ __forceinline__ unsigned short f2bf(float f){
  __bf16 h = (__bf16)f;
  return __builtin_bit_cast(unsigned short, h);
}

// ---------------------------------------------------------------------------
// K1: price LSTM. (T,V,1) -> new_prices (T,V,16). 16 lanes per vertex.
// ---------------------------------------------------------------------------
__global__ __launch_bounds__(256) void k1_price_lstm(
    const float* __restrict__ prices,
    const float* __restrict__ Wih, const float* __restrict__ Whh,
    const float* __restrict__ bih, const float* __restrict__ bhh,
    float* __restrict__ np_out){
  int tid  = threadIdx.x;
  int lane = tid & 15;
  int v    = (blockIdx.x*256 + tid) >> 4;
  float W[4][16], wih[4], b[4];
#pragma unroll
  for (int gi=0; gi<4; ++gi){
    int j = gi*16 + lane;
    const float4* wr = reinterpret_cast<const float4*>(&Whh[j*16]);
    float4 w0=wr[0], w1=wr[1], w2=wr[2], w3=wr[3];
    W[gi][0]=w0.x; W[gi][1]=w0.y; W[gi][2]=w0.z; W[gi][3]=w0.w;
    W[gi][4]=w1.x; W[gi][5]=w1.y; W[gi][6]=w1.z; W[gi][7]=w1.w;
    W[gi][8]=w2.x; W[gi][9]=w2.y; W[gi][10]=w2.z; W[gi][11]=w2.w;
    W[gi][12]=w3.x; W[gi][13]=w3.y; W[gi][14]=w3.z; W[gi][15]=w3.w;
    wih[gi] = Wih[j];
    b[gi]   = bih[j] + bhh[j];
  }
  float h = 0.f, c = 0.f;
  for (int t=0; t<TT; ++t){
    float x = prices[t*VV + v];
    float a0 = fmaf(x, wih[0], b[0]);
    float a1 = fmaf(x, wih[1], b[1]);
    float a2 = fmaf(x, wih[2], b[2]);
    float a3 = fmaf(x, wih[3], b[3]);
#pragma unroll
    for (int d=0; d<16; ++d){
      float hb = __shfl(h, d, 16);
      a0 = fmaf(hb, W[0][d], a0);
      a1 = fmaf(hb, W[1][d], a1);
      a2 = fmaf(hb, W[2][d], a2);
      a3 = fmaf(hb, W[3][d], a3);
    }
    float ig = sigmoidf_(a0);
    float fg = sigmoidf_(a1);
    float gg = tanhf(a2);
    float og = sigmoidf_(a3);
    c = fmaf(fg, c, ig*gg);
    h = og * tanhf(c);
    np_out[(size_t)(t*VV+v)*16 + lane] = h;
  }
}

// ---------------------------------------------------------------------------
// K2 fused VertexConv: block = 16 hyperedges, 256 thr = 16 te x 16 lanes.
// Thread (te, jl) owns j in {jl, jl+16}. wsum accumulated in REGISTERS over
// the k loop (no atomics anywhere). Then he_emb computed from LDS.
// ---------------------------------------------------------------------------
__global__ __launch_bounds__(256) void k2_fused(
    const float* __restrict__ np, const int* __restrict__ mem,
    const float* __restrict__ tw, const float* __restrict__ tb,
    const float* __restrict__ cw, const float* __restrict__ cb,
    float* __restrict__ he_emb){
  __shared__ float s_reg[32*16*16];   // [k][te][d]   32 KB
  __shared__ float s_tw[8*32*17];     // [kk][j][d] pad17  ~17 KB
  __shared__ float s_tb[32*32];       // [k][j]        4 KB
  __shared__ float s_wsum[16*32];     // [te][j]       2 KB
  __shared__ int   s_mem[16*32];      // [te][k]       2 KB
  __shared__ float s_cw[32];
  int tid = threadIdx.x;
  int te  = tid >> 4;       // 0..15
  int jl  = tid & 15;       // 0..15
  int te0 = blockIdx.x * 16;

  // stage member indices
  for (int i = tid; i < 512; i += 256) s_mem[i] = mem[(size_t)te0*32 + i];
  if (tid < 32) s_cw[tid] = cw[tid];
  for (int i = tid; i < 1024; i += 256) s_tb[i] = tb[i];
  __syncthreads();
  // gather member price rows: pair p=(te,k) -> s_reg[k][te][0..15]
  for (int p = tid; p < 512; p += 256){
    int pte = p >> 5, pk = p & 31;
    int gte = te0 + pte;
    int t   = gte >> 12;
    int vid = s_mem[pte*32 + pk];
    const float4* src = reinterpret_cast<const float4*>(&np[((size_t)(t*VV) + vid)*16]);
    float4* dst = reinterpret_cast<float4*>(&s_reg[(pk*16 + pte)*16]);
    dst[0] = src[0]; dst[1] = src[1]; dst[2] = src[2]; dst[3] = src[3];
  }

  float w0acc = 0.f, w1acc = 0.f;   // wsum for j=jl, j=jl+16
  for (int kc = 0; kc < 4; ++kc){
    __syncthreads();
    // stage tw chunk [8 k][32 j][16 d] -> pad 17
    for (int i = tid; i < 4096; i += 256){
      int r = i >> 4, d = i & 15;   // r = kk*32+j
      s_tw[r*17 + d] = tw[(size_t)(kc*8)*512 + i];
    }
    __syncthreads();
#pragma unroll
    for (int kk = 0; kk < 8; ++kk){
      int k = kc*8 + kk;
      const float4* rr = reinterpret_cast<const float4*>(&s_reg[(k*16 + te)*16]);
      float4 r0 = rr[0], r1 = rr[1], r2 = rr[2], r3 = rr[3];
      const float* wp0 = &s_tw[(kk*32 + jl)*17];
      const float* wp1 = &s_tw[(kk*32 + jl + 16)*17];
      float s0 = s_tb[k*32 + jl];
      float s1 = s_tb[k*32 + jl + 16];
      s0 += r0.x*wp0[0] + r0.y*wp0[1] + r0.z*wp0[2] + r0.w*wp0[3]
          + r1.x*wp0[4] + r1.y*wp0[5] + r1.z*wp0[6] + r1.w*wp0[7]
          + r2.x*wp0[8] + r2.y*wp0[9] + r2.z*wp0[10] + r2.w*wp0[11]
          + r3.x*wp0[12] + r3.y*wp0[13] + r3.z*wp0[14] + r3.w*wp0[15];
      s1 += r0.x*wp1[0] + r0.y*wp1[1] + r0.z*wp1[2] + r0.w*wp1[3]
          + r1.x*wp1[4] + r1.y*wp1[5] + r1.z*wp1[6] + r1.w*wp1[7]
          + r2.x*wp1[8] + r2.y*wp1[9] + r2.z*wp1[10] + r2.w*wp1[11]
          + r3.x*wp1[12] + r3.y*wp1[13] + r3.z*wp1[14] + r3.w*wp1[15];
      // softmax over 32 j (16 lanes x 2)
      float mx = fmaxf(s0, s1);
#pragma unroll
      for (int off = 1; off < 16; off <<= 1) mx = fmaxf(mx, __shfl_xor(mx, off, 16));
      float e0 = expf(s0 - mx), e1 = expf(s1 - mx);
      float sm = e0 + e1;
#pragma unroll
      for (int off = 1; off < 16; off <<= 1) sm += __shfl_xor(sm, off, 16);
      float f = s_cw[k] / sm;
      w0acc = fmaf(e0, f, w0acc);
      w1acc = fmaf(e1, f, w1acc);
    }
  }
  s_wsum[te*32 + jl]      = w0acc;
  s_wsum[te*32 + jl + 16] = w1acc;
  __syncthreads();
  // he_emb[te][d] = cb + sum_j wsum[te][j] * reg[j][te][d]   (d = jl)
  float acc = cb[0];
#pragma unroll
  for (int j = 0; j < 32; ++j)
    acc = fmaf(s_wsum[te*32 + j], s_reg[(j*16 + te)*16 + jl], acc);
  he_emb[((size_t)(te0 + te))*16 + jl] = acc;
}

// ---------------------------------------------------------------------------
// K3pre: pack [ec_w1 ; Wih_m] into bf16 Bbf[NPAD][KPAD], zero-padded.
// ---------------------------------------------------------------------------
__global__ __launch_bounds__(256) void k3pre(
    const float* __restrict__ w1, const float* __restrict__ wm,
    unsigned short* __restrict__ Bbf){
  int n = blockIdx.x;
  const float* src = nullptr;
  if (n < NH) src = &w1[(size_t)n*CATD];
  else if (n < NTOT) src = &wm[(size_t)(n-NH)*CATD];
  for (int kx = threadIdx.x; kx < KPAD; kx += 256){
    float v = (src != nullptr && kx < CATD) ? src[kx] : 0.f;
    Bbf[(size_t)n*KPAD + kx] = f2bf(v);
  }
}

// ---------------------------------------------------------------------------
// K3: bf16 MFMA GEMM, M-tile 32, full N=272 in one pass, BK=32 x 25 steps.
// Epilogue: hidden cols -> relu*w2 partial, atomicAdd esc[m] (intra-block
// only); pe cols -> C_pe.
// ---------------------------------------------------------------------------
__global__ __launch_bounds__(512) void k3_gemm_mfma(
    const float* __restrict__ he_emb, const float* __restrict__ node,
    const unsigned short* __restrict__ Bbf, const float* __restrict__ b1,
    const float* __restrict__ w2, float* __restrict__ esc,
    float* __restrict__ C_pe){
  __shared__ __bf16 As[32*LDT];
  __shared__ __bf16 Bs[NPAD*LDT];
  int tid = threadIdx.x;
  int m0 = blockIdx.x * 32;
  int l = tid & 63;
  int w = tid >> 6;
  int r = w & 1;
  int c = w >> 1;                       // 0..3
  int fb = (c == 0) ? 0 : (1 + 4*c);    // 0,5,9,13
  int nf = (c == 0) ? 5 : 4;
  f32x4 acc[5] = {};
  int arow = tid >> 3;                  // (threads<256) 0..31
  int akq  = (tid & 7) * 4;
  unsigned short* AsU = reinterpret_cast<unsigned short*>(As);
  unsigned short* BsU = reinterpret_cast<unsigned short*>(Bs);
  for (int step = 0; step < 25; ++step){
    int ks = step * 32;
    if (tid < 256){
      int m = m0 + arow;
      int k = ks + akq;
      float4 av = make_float4(0.f,0.f,0.f,0.f);
      if (k < 16)        av = *reinterpret_cast<const float4*>(&he_emb[(size_t)m*16 + k]);
      else if (k < CATD) av = *reinterpret_cast<const float4*>(&node[(size_t)m*BERTD + (k-16)]);
      ushort4 uv;
      uv.x = f2bf(av.x); uv.y = f2bf(av.y); uv.z = f2bf(av.z); uv.w = f2bf(av.w);
      *reinterpret_cast<ushort4*>(&AsU[arow*LDT + akq]) = uv;
    }
    for (int i = tid; i < (NPAD*32/4); i += 512){
      int n = i >> 3, kk = (i & 7) * 4;
      ushort4 uv = *reinterpret_cast<const ushort4*>(&Bbf[(size_t)n*KPAD + ks + kk]);
      *reinterpret_cast<ushort4*>(&BsU[n*LDT + kk]) = uv;
    }
    __syncthreads();
    bf16x8 af = *reinterpret_cast<const bf16x8*>(&As[(r*16 + (l & 15))*LDT + (l >> 4)*8]);
#pragma unroll
    for (int f = 0; f < 5; ++f){
      if (f < nf){
        int n16 = (fb + f) * 16;
        bf16x8 bfr = *reinterpret_cast<const bf16x8*>(&Bs[(n16 + (l & 15))*LDT + (l >> 4)*8]);
        acc[f] = __builtin_amdgcn_mfma_f32_16x16x32_bf16(af, bfr, acc[f], 0, 0, 0);
      }
    }
    __syncthreads();
  }
  // epilogue
  float p[4] = {0.f,0.f,0.f,0.f};
#pragma unroll
  for (int f = 0; f < 5; ++f){
    if (f < nf){
      int n = (fb + f)*16 + (l & 15);
      float b1n = (n < NH) ? b1[n] : 0.f;
      float w2n = (n < NH) ? w2[n] : 0.f;
#pragma unroll
      for (int i = 0; i < 4; ++i){
        float v = acc[f][i];
        if (n < NH){
          p[i] += fmaxf(v + b1n, 0.f) * w2n;
        } else if (n < NTOT){
          int m = m0 + r*16 + (l >> 4)*4 + i;
          C_pe[(size_t)m*64 + (n - NH)] = v;
        }
      }
    }
  }
#pragma unroll
  for (int i = 0; i < 4; ++i){
#pragma unroll
    for (int off = 1; off < 16; off <<= 1) p[i] += __shfl_xor(p[i], off, 16);
    if ((l & 15) == 0){
      int m = m0 + r*16 + (l >> 4)*4 + i;
      atomicAdd(&esc[m], p[i]);
    }
  }
}

// ---------------------------------------------------------------------------
// K4: per (t,v): softmax over D=8 edge scores (b2 cancels), blend C_pe rows
// -> g_in (T,V,64). One wave per (t,v).
// ---------------------------------------------------------------------------
__global__ __launch_bounds__(256) void k4_edge_gather(
    const int* __restrict__ ve, const float* __restrict__ esc,
    const float* __restrict__ C_pe, float* __restrict__ g_in){
  int tid = threadIdx.x;
  int lane = tid & 63;
  int tv = blockIdx.x*4 + (tid >> 6);
  int t = tv >> 12;
  const int* vp = &ve[(size_t)tv*8];
  int e[8]; float w[8];
  float mx = -1e30f;
#pragma unroll
  for (int d = 0; d < 8; ++d){
    e[d] = vp[d];
    w[d] = esc[(t << 12) + e[d]];
    mx = fmaxf(mx, w[d]);
  }
  float s = 0.f;
#pragma unroll
  for (int d = 0; d < 8; ++d){ w[d] = expf(w[d]-mx); s += w[d]; }
  float inv = 1.f/s;
  float a = 0.f;
#pragma unroll
  for (int d = 0; d < 8; ++d)
    a = fmaf(w[d], C_pe[(size_t)((t << 12) + e[d])*64 + lane], a);
  g_in[(size_t)tv*64 + lane] = a * inv;
}

// ---------------------------------------------------------------------------
// K5: second LSTM (input pre-projected in g_in) + residual. 16 lanes/vertex.
// ---------------------------------------------------------------------------
__global__ __launch_bounds__(256) void k5_lstm2(
    const float* __restrict__ g_in, const float* __restrict__ Whh,
    const float* __restrict__ bih, const float* __restrict__ bhh,
    const float* __restrict__ np, float* __restrict__ la){
  int tid  = threadIdx.x;
  int lane = tid & 15;
  int v    = (blockIdx.x*256 + tid) >> 4;
  float W[4][16], b[4];
#pragma unroll
  for (int gi=0; gi<4; ++gi){
    int j = gi*16 + lane;
    const float4* wr = reinterpret_cast<const float4*>(&Whh[j*16]);
    float4 w0=wr[0], w1=wr[1], w2=wr[2], w3=wr[3];
    W[gi][0]=w0.x; W[gi][1]=w0.y; W[gi][2]=w0.z; W[gi][3]=w0.w;
    W[gi][4]=w1.x; W[gi][5]=w1.y; W[gi][6]=w1.z; W[gi][7]=w1.w;
    W[gi][8]=w2.x; W[gi][9]=w2.y; W[gi][10]=w2.z; W[gi][11]=w2.w;
    W[gi][12]=w3.x; W[gi][13]=w3.y; W[gi][14]=w3.z; W[gi][15]=w3.w;
    b[gi] = bih[j] + bhh[j];
  }
  float h = 0.f, c = 0.f;
  for (int t=0; t<TT; ++t){
    const float* gi_p = &g_in[(size_t)(t*VV+v)*64];
    float a0 = gi_p[lane]      + b[0];
    float a1 = gi_p[16 + lane] + b[1];
    float a2 = gi_p[32 + lane] + b[2];
    float a3 = gi_p[48 + lane] + b[3];
#pragma unroll
    for (int d=0; d<16; ++d){
      float hb = __shfl(h, d, 16);
      a0 = fmaf(hb, W[0][d], a0);
      a1 = fmaf(hb, W[1][d], a1);
      a2 = fmaf(hb, W[2][d], a2);
      a3 = fmaf(hb, W[3][d], a3);
    }
    float ig = sigmoidf_(a0);
    float fg = sigmoidf_(a1);
    float gg = tanhf(a2);
    float og = sigmoidf_(a3);
    c = fmaf(fg, c, ig*gg);
    h = og * tanhf(c);
    la[(size_t)(t*VV+v)*16 + lane] = h + np[(size_t)(t*VV+v)*16 + lane];
  }
}

// ---------------------------------------------------------------------------
// K6: attention + tanh proj + FC. 16 lanes per vertex.
// ---------------------------------------------------------------------------
__global__ __launch_bounds__(256) void k6_attn_fc(
    const float* __restrict__ la, const float* __restrict__ ain,
    const float* __restrict__ aout, const float* __restrict__ fcw,
    const float* __restrict__ fcb, float* __restrict__ out){
  __shared__ float s_ain[16*17];
  __shared__ float s_aout[16*33];
  __shared__ float s_fc[32];
  __shared__ float s_fcb[2];
  int tid = threadIdx.x;
  { int j = tid >> 4, d = tid & 15; s_ain[j*17+d] = ain[tid]; }
  for (int i = tid; i < 512; i += 256){ int j = i >> 5, d = i & 31; s_aout[j*33+d] = aout[i]; }
  if (tid < 32) s_fc[tid] = fcw[tid];
  if (tid < 2)  s_fcb[tid] = fcb[tid];
  __syncthreads();
  int lane = tid & 15;
  int v = (blockIdx.x*256 + tid) >> 4;
  float l0 = la[(size_t)(0*VV+v)*16 + lane];
  float l1 = la[(size_t)(1*VV+v)*16 + lane];
  float l2 = la[(size_t)(2*VV+v)*16 + lane];
  float l3 = la[(size_t)(3*VV+v)*16 + lane];
  float q = 0.f;
#pragma unroll
  for (int d=0; d<16; ++d){
    float bb = __shfl(l3, d, 16);
    q = fmaf(bb, s_ain[lane*17+d], q);
  }
  float aw0 = q*l0, aw1 = q*l1, aw2 = q*l2, aw3 = q*l3;
#pragma unroll
  for (int off=1; off<16; off<<=1){
    aw0 += __shfl_xor(aw0, off, 16);
    aw1 += __shfl_xor(aw1, off, 16);
    aw2 += __shfl_xor(aw2, off, 16);
    aw3 += __shfl_xor(aw3, off, 16);
  }
  float mx = fmaxf(fmaxf(aw0,aw1), fmaxf(aw2,aw3));
  aw0 = expf(aw0-mx); aw1 = expf(aw1-mx); aw2 = expf(aw2-mx); aw3 = expf(aw3-mx);
  float inv = 1.f/(aw0+aw1+aw2+aw3);
  float mix = (aw0*l0 + aw1*l1 + aw2*l2 + aw3*l3) * inv;
  float a = 0.f;
#pragma unroll
  for (int d=0; d<16; ++d){
    float m  = __shfl(mix, d, 16);
    float qq = __shfl(q,  d, 16);
    a = fmaf(m,  s_aout[lane*33+d],    a);
    a = fmaf(qq, s_aout[lane*33+16+d], a);
  }
  float at = tanhf(a);
  float p0 = at * s_fc[lane];
  float p1 = at * s_fc[16+lane];
#pragma unroll
  for (int off=1; off<16; off<<=1){
    p0 += __shfl_xor(p0, off, 16);
    p1 += __shfl_xor(p1, off, 16);
  }
  if (lane == 0){
    out[(size_t)v*2 + 0] = p0 + s_fcb[0];
    out[(size_t)v*2 + 1] = p1 + s_fcb[1];
  }
}

// ---------------------------------------------------------------------------
extern "C" void kernel_launch(void* const* d_in, const int* in_sizes, int n_in,
                              void* d_out, int out_size, void* d_ws, size_t ws_size,
                              hipStream_t stream){
  const float* prices = (const float*)d_in[0];
  const float* node   = (const float*)d_in[1];
  const int*   mem    = (const int*)d_in[2];
  const int*   ve     = (const int*)d_in[3];
  const float* Wih_p  = (const float*)d_in[4];
  const float* Whh_p  = (const float*)d_in[5];
  const float* bih_p  = (const float*)d_in[6];
  const float* bhh_p  = (const float*)d_in[7];
  const float* Wih_m  = (const float*)d_in[8];
  const float* Whh_m  = (const float*)d_in[9];
  const float* bih_m  = (const float*)d_in[10];
  const float* bhh_m  = (const float*)d_in[11];
  const float* tw     = (const float*)d_in[12];
  const float* tb     = (const float*)d_in[13];
  const float* cw     = (const float*)d_in[14];
  const float* cb     = (const float*)d_in[15];
  const float* w1     = (const float*)d_in[16];
  const float* b1     = (const float*)d_in[17];
  const float* w2     = (const float*)d_in[18];
  // d_in[19] = ec_b2: cancels in softmax, unused
  const float* ain    = (const float*)d_in[20];
  const float* aout   = (const float*)d_in[21];
  const float* fcw    = (const float*)d_in[22];
  const float* fcb    = (const float*)d_in[23];

  // workspace layout (floats)
  float* np_buf = (float*)d_ws;                       // T*V*16      = 262144
  float* he_emb = np_buf + (size_t)TT*VV*HH;          // T*E*16      = 262144
  float* esc    = he_emb + (size_t)TT*EE*HH;          // T*E         = 16384
  float* C_pe   = esc    + (size_t)TT*EE;             // 16384*64    = 1048576
  float* g_in   = C_pe   + (size_t)TT*EE*64;          // T*V*64      = 1048576
  float* la_buf = g_in   + (size_t)TT*VV*64;          // T*V*16      = 262144
  unsigned short* Bbf = (unsigned short*)(la_buf + (size_t)TT*VV*HH); // 272*800 u16

  hipMemsetAsync(esc, 0, (size_t)TT*EE*sizeof(float), stream);

  k1_price_lstm<<<(VV*16)/256, 256, 0, stream>>>(prices, Wih_p, Whh_p, bih_p, bhh_p, np_buf);
  k3pre<<<NPAD, 256, 0, stream>>>(w1, Wih_m, Bbf);
  k2_fused<<<(TT*EE)/16, 256, 0, stream>>>(np_buf, mem, tw, tb, cw, cb, he_emb);
  k3_gemm_mfma<<<(TT*EE)/32, 512, 0, stream>>>(he_emb, node, Bbf, b1, w2, esc, C_pe);
  k4_edge_gather<<<(TT*VV)/4, 256, 0, stream>>>(ve, esc, C_pe, g_in);
  k5_lstm2<<<(VV*16)/256, 256, 0, stream>>>(g_in, Whh_m, bih_m, bhh_m, np_buf, la_buf);
  k6_attn_fc<<<(VV*16)/256, 256, 0, stream>>>(la_buf, ain, aout, fcw, fcb, (float*)d_out);
}

// Round 5
// 250.170 us; speedup vs baseline: 4.0173x; 1.0569x over previous
//
#include <hip/hip_runtime.h>
#include <hip/hip_bf16.h>
#include <math.h>

// Problem constants
#define TT 4
#define VV 4096
#define EE 4096
#define KK 32
#define DD 8
#define HH 16
#define BERTD 768
#define CATD 784
#define NH 196      // CAT/4 hidden units of EdgeConv MLP
#define NTOT 260    // 196 hidden + 64 pe (Wih_m projection)
#define KPAD2 832   // K padded to 26*32 (even step count for ping-pong)
#define NPAD2 288   // N padded to 18*16
#define LDT 40      // LDS row stride in halves (80B, 16B-aligned, bank-friendly)

typedef __bf16 bf16x8 __attribute__((ext_vector_type(8)));
typedef float  f32x4  __attribute__((ext_vector_type(4)));

__device__ __forceinline__ float sigmoidf_(float x){ return 1.0f/(1.0f+expf(-x)); }
__device__ __forceinline__ unsigned short f2bf(float f){
  __bf16 h = (__bf16)f;
  return __builtin_bit_cast(unsigned short, h);
}
__device__ __forceinline__ float bf2f(unsigned short u){
  unsigned int x = ((unsigned int)u) << 16;
  return __builtin_bit_cast(float, x);
}

// ---------------------------------------------------------------------------
// kP: fused prep.
//  blocks [0,256):    price LSTM (16 lanes/vertex) -> np (T,V,16) f32
//  blocks [256,544):  pack [ec_w1 ; Wih_m] -> Bbf[288][832] bf16 (zero-pad)
//  blocks [544,546):  pack vc_trans_w -> twbf[32*32][16] bf16
//  blocks [546,562):  zero esc (16384 f32)
// ---------------------------------------------------------------------------
__global__ __launch_bounds__(256) void kP(
    const float* __restrict__ prices,
    const float* __restrict__ Wih, const float* __restrict__ Whh,
    const float* __restrict__ bih, const float* __restrict__ bhh,
    float* __restrict__ np_out,
    const float* __restrict__ w1, const float* __restrict__ wm,
    unsigned short* __restrict__ Bbf,
    const float* __restrict__ tw, unsigned short* __restrict__ twbf,
    float* __restrict__ esc){
  int b = blockIdx.x;
  int tid = threadIdx.x;
  if (b < 256){
    int lane = tid & 15;
    int v    = (b*256 + tid) >> 4;
    float W[4][16], wih[4], bb[4];
#pragma unroll
    for (int gi=0; gi<4; ++gi){
      int j = gi*16 + lane;
      const float4* wr = reinterpret_cast<const float4*>(&Whh[j*16]);
      float4 w0=wr[0], w1v=wr[1], w2v=wr[2], w3v=wr[3];
      W[gi][0]=w0.x; W[gi][1]=w0.y; W[gi][2]=w0.z; W[gi][3]=w0.w;
      W[gi][4]=w1v.x; W[gi][5]=w1v.y; W[gi][6]=w1v.z; W[gi][7]=w1v.w;
      W[gi][8]=w2v.x; W[gi][9]=w2v.y; W[gi][10]=w2v.z; W[gi][11]=w2v.w;
      W[gi][12]=w3v.x; W[gi][13]=w3v.y; W[gi][14]=w3v.z; W[gi][15]=w3v.w;
      wih[gi] = Wih[j];
      bb[gi]  = bih[j] + bhh[j];
    }
    float h = 0.f, c = 0.f;
    for (int t=0; t<TT; ++t){
      float x = prices[t*VV + v];
      float a0 = fmaf(x, wih[0], bb[0]);
      float a1 = fmaf(x, wih[1], bb[1]);
      float a2 = fmaf(x, wih[2], bb[2]);
      float a3 = fmaf(x, wih[3], bb[3]);
#pragma unroll
      for (int d=0; d<16; ++d){
        float hb = __shfl(h, d, 16);
        a0 = fmaf(hb, W[0][d], a0);
        a1 = fmaf(hb, W[1][d], a1);
        a2 = fmaf(hb, W[2][d], a2);
        a3 = fmaf(hb, W[3][d], a3);
      }
      float ig = sigmoidf_(a0);
      float fg = sigmoidf_(a1);
      float gg = tanhf(a2);
      float og = sigmoidf_(a3);
      c = fmaf(fg, c, ig*gg);
      h = og * tanhf(c);
      np_out[(size_t)(t*VV+v)*16 + lane] = h;
    }
  } else if (b < 544){
    int n = b - 256;
    const float* src = nullptr;
    if (n < NH)        src = &w1[(size_t)n*CATD];
    else if (n < NTOT) src = &wm[(size_t)(n-NH)*CATD];
    for (int kx = tid; kx < KPAD2; kx += 256){
      float v = (src != nullptr && kx < CATD) ? src[kx] : 0.f;
      Bbf[(size_t)n*KPAD2 + kx] = f2bf(v);
    }
  } else if (b < 546){
    // 1024 rows (k*32+j), 16 floats each
    int base = (b - 544) * 512;
#pragma unroll
    for (int rr = 0; rr < 2; ++rr){
      int r = base + tid*2 + rr;
      const float* s = &tw[(size_t)r*16];
#pragma unroll
      for (int d = 0; d < 16; ++d) twbf[(size_t)r*16 + d] = f2bf(s[d]);
    }
  } else {
    int idx = ((b - 546)*256 + tid)*4;
    float4 z = make_float4(0.f,0.f,0.f,0.f);
    *reinterpret_cast<float4*>(&esc[idx]) = z;
  }
}

// ---------------------------------------------------------------------------
// K2: VertexConv via MFMA. Block = 16 hyperedges (te), 256 thr, 4 waves.
// GEMM1 per k: S[te][j] = reg[te,:16] . twbf[k][j,:16] + tb[k][j], done with
// mfma_f32_16x16x32_bf16 (k 16..31 zero via masked fragments; tb as C-init).
// Wave w handles k in [8w, 8w+8). Softmax over j in the MFMA C-layout
// (row te=(l>>4)*4+i, col j=l&15), wsum accumulated in registers.
// Then he_emb[te][d] = cb + sum_j wsum[j]*reg[j][te][d] from LDS.
// ---------------------------------------------------------------------------
__global__ __launch_bounds__(256) void k2_fused(
    const float* __restrict__ np, const int* __restrict__ mem,
    const unsigned short* __restrict__ twbf, const float* __restrict__ tb,
    const float* __restrict__ cw, const float* __restrict__ cb,
    float* __restrict__ he_emb){
  __shared__ unsigned short s_reg[32*16*16];  // [k][te][d] bf16, 16 KB
  __shared__ float s_wsumP[4][16][32];        // per-wave partial wsum, 8 KB
  __shared__ int   s_mem[512];
  int tid = threadIdx.x;
  int te0 = blockIdx.x * 16;
  for (int i = tid; i < 512; i += 256) s_mem[i] = mem[(size_t)te0*32 + i];
  __syncthreads();
  // gather member rows -> bf16 [k][te][16]; lanes write consecutive rows
  for (int p = tid; p < 512; p += 256){
    int gte = p & 15, gk = p >> 4;
    int t   = (te0 + gte) >> 12;
    int vid = s_mem[gte*32 + gk];
    const float4* src = reinterpret_cast<const float4*>(&np[((size_t)(t*VV) + vid)*16]);
    float4 f0 = src[0], f1 = src[1], f2 = src[2], f3 = src[3];
    uint4 u0, u1;
    u0.x = (unsigned)f2bf(f0.x) | ((unsigned)f2bf(f0.y) << 16);
    u0.y = (unsigned)f2bf(f0.z) | ((unsigned)f2bf(f0.w) << 16);
    u0.z = (unsigned)f2bf(f1.x) | ((unsigned)f2bf(f1.y) << 16);
    u0.w = (unsigned)f2bf(f1.z) | ((unsigned)f2bf(f1.w) << 16);
    u1.x = (unsigned)f2bf(f2.x) | ((unsigned)f2bf(f2.y) << 16);
    u1.y = (unsigned)f2bf(f2.z) | ((unsigned)f2bf(f2.w) << 16);
    u1.z = (unsigned)f2bf(f3.x) | ((unsigned)f2bf(f3.y) << 16);
    u1.w = (unsigned)f2bf(f3.z) | ((unsigned)f2bf(f3.w) << 16);
    uint4* dst = reinterpret_cast<uint4*>(&s_reg[(gk*16 + gte)*16]);
    dst[0] = u0; dst[1] = u1;
  }
  __syncthreads();
  int l = tid & 63;
  int w = tid >> 6;
  int lj = l & 15;       // j (col) lane
  int lg = l >> 4;       // row group
  float w0acc[4] = {0.f,0.f,0.f,0.f};
  float w1acc[4] = {0.f,0.f,0.f,0.f};
#pragma unroll
  for (int kk = 0; kk < 8; ++kk){
    int k = w*8 + kk;
    bf16x8 af = 0, b0 = 0, b1v = 0;
    if (l < 32){
      af  = *reinterpret_cast<const bf16x8*>(&s_reg[(k*16 + lj)*16 + lg*8]);
      b0  = *reinterpret_cast<const bf16x8*>(&twbf[((size_t)k*32 + lj)*16 + lg*8]);
      b1v = *reinterpret_cast<const bf16x8*>(&twbf[((size_t)k*32 + 16 + lj)*16 + lg*8]);
    }
    float tb0 = tb[k*32 + lj];
    float tb1 = tb[k*32 + 16 + lj];
    f32x4 c0 = {tb0, tb0, tb0, tb0};
    f32x4 c1 = {tb1, tb1, tb1, tb1};
    f32x4 s0 = __builtin_amdgcn_mfma_f32_16x16x32_bf16(af, b0,  c0, 0, 0, 0);
    f32x4 s1 = __builtin_amdgcn_mfma_f32_16x16x32_bf16(af, b1v, c1, 0, 0, 0);
    float cwk = cw[k];
#pragma unroll
    for (int i = 0; i < 4; ++i){
      float v0 = s0[i], v1 = s1[i];
      float m = fmaxf(v0, v1);
#pragma unroll
      for (int off = 1; off < 16; off <<= 1) m = fmaxf(m, __shfl_xor(m, off, 16));
      float e0 = expf(v0 - m), e1 = expf(v1 - m);
      float sm = e0 + e1;
#pragma unroll
      for (int off = 1; off < 16; off <<= 1) sm += __shfl_xor(sm, off, 16);
      float f = cwk / sm;
      w0acc[i] = fmaf(e0, f, w0acc[i]);
      w1acc[i] = fmaf(e1, f, w1acc[i]);
    }
  }
#pragma unroll
  for (int i = 0; i < 4; ++i){
    int ter = lg*4 + i;
    s_wsumP[w][ter][lj]      = w0acc[i];
    s_wsumP[w][ter][16 + lj] = w1acc[i];
  }
  __syncthreads();
  // he phase: thread (te = tid>>4, d = tid&15)
  int te = tid >> 4, d = tid & 15;
  float he = cb[0];
#pragma unroll
  for (int j = 0; j < 32; ++j){
    float ws = s_wsumP[0][te][j] + s_wsumP[1][te][j]
             + s_wsumP[2][te][j] + s_wsumP[3][te][j];
    he = fmaf(ws, bf2f(s_reg[(j*16 + te)*16 + d]), he);
  }
  he_emb[((size_t)(te0 + te))*16 + d] = he;
}

// ---------------------------------------------------------------------------
// K3: bf16 MFMA GEMM. M-tile 64, N=288 (18 frags), BK=32 x 26 steps.
// 4 waves in 2m x 2n: wave (wr,wc) owns m-frags {2wr,2wr+1}, n-frags wc*9..+8.
// Register ping-pong pipeline: loads for step s+1 issued during compute of s.
// Epilogue: hidden cols -> relu*w2 reduce -> atomicAdd esc; pe cols -> C_pe.
// ---------------------------------------------------------------------------
__device__ __forceinline__ void k3_load(int step, int tid, int m0,
    const float* __restrict__ he_emb, const float* __restrict__ node,
    const unsigned short* __restrict__ Bbf,
    float4& a0, float4& a1, uint4 (&bb)[5]){
  int ks = step * 32;
  int arow = tid >> 2, ak8 = (tid & 3) * 8;
  int m = m0 + arow;
  int k = ks + ak8;
  if (k < 16){
    const float4* p = reinterpret_cast<const float4*>(&he_emb[(size_t)m*16 + k]);
    a0 = p[0]; a1 = p[1];
  } else if (k < CATD){
    const float4* p = reinterpret_cast<const float4*>(&node[(size_t)m*BERTD + (k-16)]);
    a0 = p[0]; a1 = p[1];
  } else {
    a0 = make_float4(0.f,0.f,0.f,0.f); a1 = a0;
  }
#pragma unroll
  for (int ii = 0; ii < 5; ++ii){
    int i = tid + ii*256;
    if (i < 1152)
      bb[ii] = *reinterpret_cast<const uint4*>(&Bbf[(size_t)(i>>2)*KPAD2 + ks + (i&3)*8]);
  }
}

__device__ __forceinline__ void k3_store(int tid, unsigned short* AsU, unsigned short* BsU,
    const float4& a0, const float4& a1, const uint4 (&bb)[5]){
  int arow = tid >> 2, ak8 = (tid & 3) * 8;
  uint4 ua;
  ua.x = (unsigned)f2bf(a0.x) | ((unsigned)f2bf(a0.y) << 16);
  ua.y = (unsigned)f2bf(a0.z) | ((unsigned)f2bf(a0.w) << 16);
  ua.z = (unsigned)f2bf(a1.x) | ((unsigned)f2bf(a1.y) << 16);
  ua.w = (unsigned)f2bf(a1.z) | ((unsigned)f2bf(a1.w) << 16);
  *reinterpret_cast<uint4*>(&AsU[arow*LDT + ak8]) = ua;
#pragma unroll
  for (int ii = 0; ii < 5; ++ii){
    int i = tid + ii*256;
    if (i < 1152)
      *reinterpret_cast<uint4*>(&BsU[(i>>2)*LDT + (i&3)*8]) = bb[ii];
  }
}

__global__ __launch_bounds__(256) void k3_gemm_mfma(
    const float* __restrict__ he_emb, const float* __restrict__ node,
    const unsigned short* __restrict__ Bbf, const float* __restrict__ b1,
    const float* __restrict__ w2, float* __restrict__ esc,
    float* __restrict__ C_pe){
  __shared__ unsigned short AsU[64*LDT];
  __shared__ unsigned short BsU[NPAD2*LDT];
  int tid = threadIdx.x;
  int m0 = blockIdx.x * 64;
  int l = tid & 63;
  int w = tid >> 6;
  int wr = w & 1, wc = w >> 1;
  f32x4 acc[2][9] = {};
  float4 a0A, a1A, a0B, a1B;
  uint4 bbA[5], bbB[5];

  k3_load(0, tid, m0, he_emb, node, Bbf, a0A, a1A, bbA);
  for (int it = 0; it < 26; it += 2){
    k3_store(tid, AsU, BsU, a0A, a1A, bbA);
    __syncthreads();
    if (it + 1 < 26) k3_load(it+1, tid, m0, he_emb, node, Bbf, a0B, a1B, bbB);
    {
      bf16x8 af0 = *reinterpret_cast<const bf16x8*>(&AsU[((wr*2+0)*16 + (l&15))*LDT + (l>>4)*8]);
      bf16x8 af1 = *reinterpret_cast<const bf16x8*>(&AsU[((wr*2+1)*16 + (l&15))*LDT + (l>>4)*8]);
#pragma unroll
      for (int j = 0; j < 9; ++j){
        bf16x8 bfv = *reinterpret_cast<const bf16x8*>(&BsU[((wc*9+j)*16 + (l&15))*LDT + (l>>4)*8]);
        acc[0][j] = __builtin_amdgcn_mfma_f32_16x16x32_bf16(af0, bfv, acc[0][j], 0, 0, 0);
        acc[1][j] = __builtin_amdgcn_mfma_f32_16x16x32_bf16(af1, bfv, acc[1][j], 0, 0, 0);
      }
    }
    __syncthreads();
    k3_store(tid, AsU, BsU, a0B, a1B, bbB);
    __syncthreads();
    if (it + 2 < 26) k3_load(it+2, tid, m0, he_emb, node, Bbf, a0A, a1A, bbA);
    {
      bf16x8 af0 = *reinterpret_cast<const bf16x8*>(&AsU[((wr*2+0)*16 + (l&15))*LDT + (l>>4)*8]);
      bf16x8 af1 = *reinterpret_cast<const bf16x8*>(&AsU[((wr*2+1)*16 + (l&15))*LDT + (l>>4)*8]);
#pragma unroll
      for (int j = 0; j < 9; ++j){
        bf16x8 bfv = *reinterpret_cast<const bf16x8*>(&BsU[((wc*9+j)*16 + (l&15))*LDT + (l>>4)*8]);
        acc[0][j] = __builtin_amdgcn_mfma_f32_16x16x32_bf16(af0, bfv, acc[0][j], 0, 0, 0);
        acc[1][j] = __builtin_amdgcn_mfma_f32_16x16x32_bf16(af1, bfv, acc[1][j], 0, 0, 0);
      }
    }
    __syncthreads();
  }
  // epilogue
  float p[2][4] = {{0.f,0.f,0.f,0.f},{0.f,0.f,0.f,0.f}};
#pragma unroll
  for (int j = 0; j < 9; ++j){
    int n = (wc*9 + j)*16 + (l & 15);
    float b1n = (n < NH) ? b1[n] : 0.f;
    float w2n = (n < NH) ? w2[n] : 0.f;
#pragma unroll
    for (int i = 0; i < 2; ++i){
#pragma unroll
      for (int q = 0; q < 4; ++q){
        float v = acc[i][j][q];
        if (n < NH){
          p[i][q] += fmaxf(v + b1n, 0.f) * w2n;
        } else if (n < NTOT){
          int m = m0 + (wr*2+i)*16 + (l >> 4)*4 + q;
          C_pe[(size_t)m*64 + (n - NH)] = v;
        }
      }
    }
  }
#pragma unroll
  for (int i = 0; i < 2; ++i){
#pragma unroll
    for (int q = 0; q < 4; ++q){
      float v = p[i][q];
#pragma unroll
      for (int off = 1; off < 16; off <<= 1) v += __shfl_xor(v, off, 16);
      if ((l & 15) == 0){
        int m = m0 + (wr*2+i)*16 + (l >> 4)*4 + q;
        atomicAdd(&esc[m], v);
      }
    }
  }
}

// ---------------------------------------------------------------------------
// K456: fused edge-gather + LSTM2 + attention + FC. 16 lanes per vertex.
// Per t: softmax over D=8 edge scores (b2 cancels), blend projected C_pe rows
// directly into the 4 gate pre-activations; LSTM step; la kept in registers;
// then torchnlp 'general' attention + tanh proj + final classifier.
// ---------------------------------------------------------------------------
__global__ __launch_bounds__(256) void k456(
    const int* __restrict__ ve, const float* __restrict__ esc,
    const float* __restrict__ C_pe, const float* __restrict__ np,
    const float* __restrict__ Whh, const float* __restrict__ bih,
    const float* __restrict__ bhh,
    const float* __restrict__ ain, const float* __restrict__ aout,
    const float* __restrict__ fcw, const float* __restrict__ fcb,
    float* __restrict__ out){
  __shared__ float s_ain[16*17];
  __shared__ float s_aout[16*33];
  __shared__ float s_fc[32];
  __shared__ float s_fcb[2];
  int tid = threadIdx.x;
  { int j = tid >> 4, d = tid & 15; s_ain[j*17+d] = ain[tid]; }
  for (int i = tid; i < 512; i += 256){ int j = i >> 5, d = i & 31; s_aout[j*33+d] = aout[i]; }
  if (tid < 32) s_fc[tid] = fcw[tid];
  if (tid < 2)  s_fcb[tid] = fcb[tid];
  int lane = tid & 15;
  int v = (blockIdx.x*256 + tid) >> 4;
  float W[4][16], b[4];
#pragma unroll
  for (int gi=0; gi<4; ++gi){
    int j = gi*16 + lane;
    const float4* wr = reinterpret_cast<const float4*>(&Whh[j*16]);
    float4 w0=wr[0], w1=wr[1], w2=wr[2], w3=wr[3];
    W[gi][0]=w0.x; W[gi][1]=w0.y; W[gi][2]=w0.z; W[gi][3]=w0.w;
    W[gi][4]=w1.x; W[gi][5]=w1.y; W[gi][6]=w1.z; W[gi][7]=w1.w;
    W[gi][8]=w2.x; W[gi][9]=w2.y; W[gi][10]=w2.z; W[gi][11]=w2.w;
    W[gi][12]=w3.x; W[gi][13]=w3.y; W[gi][14]=w3.z; W[gi][15]=w3.w;
    b[gi] = bih[j] + bhh[j];
  }
  __syncthreads();
  float h = 0.f, c = 0.f;
  float la0, la1, la2, la3;
#pragma unroll
  for (int t=0; t<TT; ++t){
    const int* vp = &ve[((size_t)(t*VV) + v)*8];
    int e[8]; float wv[8];
    float mx = -1e30f;
#pragma unroll
    for (int d = 0; d < 8; ++d){
      e[d] = vp[d];
      wv[d] = esc[(t << 12) + e[d]];
      mx = fmaxf(mx, wv[d]);
    }
    float s = 0.f;
#pragma unroll
    for (int d = 0; d < 8; ++d){ wv[d] = expf(wv[d]-mx); s += wv[d]; }
    float inv = 1.f/s;
#pragma unroll
    for (int d = 0; d < 8; ++d) wv[d] *= inv;
    float g0 = b[0], g1 = b[1], g2 = b[2], g3 = b[3];
#pragma unroll
    for (int d = 0; d < 8; ++d){
      const float* cp = &C_pe[(size_t)((t << 12) + e[d])*64];
      g0 = fmaf(wv[d], cp[lane],      g0);
      g1 = fmaf(wv[d], cp[16 + lane], g1);
      g2 = fmaf(wv[d], cp[32 + lane], g2);
      g3 = fmaf(wv[d], cp[48 + lane], g3);
    }
#pragma unroll
    for (int d=0; d<16; ++d){
      float hb = __shfl(h, d, 16);
      g0 = fmaf(hb, W[0][d], g0);
      g1 = fmaf(hb, W[1][d], g1);
      g2 = fmaf(hb, W[2][d], g2);
      g3 = fmaf(hb, W[3][d], g3);
    }
    float ig = sigmoidf_(g0);
    float fg = sigmoidf_(g1);
    float gg = tanhf(g2);
    float og = sigmoidf_(g3);
    c = fmaf(fg, c, ig*gg);
    h = og * tanhf(c);
    float la = h + np[(size_t)(t*VV+v)*16 + lane];
    if (t == 0) la0 = la; else if (t == 1) la1 = la;
    else if (t == 2) la2 = la; else la3 = la;
  }
  // attention
  float q = 0.f;
#pragma unroll
  for (int d=0; d<16; ++d){
    float bb = __shfl(la3, d, 16);
    q = fmaf(bb, s_ain[lane*17+d], q);
  }
  float aw0 = q*la0, aw1 = q*la1, aw2 = q*la2, aw3 = q*la3;
#pragma unroll
  for (int off=1; off<16; off<<=1){
    aw0 += __shfl_xor(aw0, off, 16);
    aw1 += __shfl_xor(aw1, off, 16);
    aw2 += __shfl_xor(aw2, off, 16);
    aw3 += __shfl_xor(aw3, off, 16);
  }
  float mx = fmaxf(fmaxf(aw0,aw1), fmaxf(aw2,aw3));
  aw0 = expf(aw0-mx); aw1 = expf(aw1-mx); aw2 = expf(aw2-mx); aw3 = expf(aw3-mx);
  float inv = 1.f/(aw0+aw1+aw2+aw3);
  float mix = (aw0*la0 + aw1*la1 + aw2*la2 + aw3*la3) * inv;
  float a = 0.f;
#pragma unroll
  for (int d=0; d<16; ++d){
    float m  = __shfl(mix, d, 16);
    float qq = __shfl(q,  d, 16);
    a = fmaf(m,  s_aout[lane*33+d],    a);
    a = fmaf(qq, s_aout[lane*33+16+d], a);
  }
  float at = tanhf(a);
  float p0 = at * s_fc[lane];
  float p1 = at * s_fc[16+lane];
#pragma unroll
  for (int off=1; off<16; off<<=1){
    p0 += __shfl_xor(p0, off, 16);
    p1 += __shfl_xor(p1, off, 16);
  }
  if (lane == 0){
    out[(size_t)v*2 + 0] = p0 + s_fcb[0];
    out[(size_t)v*2 + 1] = p1 + s_fcb[1];
  }
}

// ---------------------------------------------------------------------------
extern "C" void kernel_launch(void* const* d_in, const int* in_sizes, int n_in,
                              void* d_out, int out_size, void* d_ws, size_t ws_size,
                              hipStream_t stream){
  const float* prices = (const float*)d_in[0];
  const float* node   = (const float*)d_in[1];
  const int*   mem    = (const int*)d_in[2];
  const int*   ve     = (const int*)d_in[3];
  const float* Wih_p  = (const float*)d_in[4];
  const float* Whh_p  = (const float*)d_in[5];
  const float* bih_p  = (const float*)d_in[6];
  const float* bhh_p  = (const float*)d_in[7];
  const float* Wih_m  = (const float*)d_in[8];
  const float* Whh_m  = (const float*)d_in[9];
  const float* bih_m  = (const float*)d_in[10];
  const float* bhh_m  = (const float*)d_in[11];
  const float* tw     = (const float*)d_in[12];
  const float* tb     = (const float*)d_in[13];
  const float* cw     = (const float*)d_in[14];
  const float* cb     = (const float*)d_in[15];
  const float* w1     = (const float*)d_in[16];
  const float* b1     = (const float*)d_in[17];
  const float* w2     = (const float*)d_in[18];
  // d_in[19] = ec_b2: cancels in softmax, unused
  const float* ain    = (const float*)d_in[20];
  const float* aout   = (const float*)d_in[21];
  const float* fcw    = (const float*)d_in[22];
  const float* fcb    = (const float*)d_in[23];

  // workspace layout
  float* np_buf = (float*)d_ws;                       // T*V*16      = 262144 f
  float* he_emb = np_buf + (size_t)TT*VV*HH;          // T*E*16      = 262144 f
  float* esc    = he_emb + (size_t)TT*EE*HH;          // T*E         = 16384 f
  float* C_pe   = esc    + (size_t)TT*EE;             // 16384*64    = 1048576 f
  unsigned short* Bbf  = (unsigned short*)(C_pe + (size_t)TT*EE*64); // 288*832 u16
  unsigned short* twbf = Bbf + (size_t)NPAD2*KPAD2;                  // 1024*16 u16

  kP<<<562, 256, 0, stream>>>(prices, Wih_p, Whh_p, bih_p, bhh_p, np_buf,
                              w1, Wih_m, Bbf, tw, twbf, esc);
  k2_fused<<<(TT*EE)/16, 256, 0, stream>>>(np_buf, mem, twbf, tb, cw, cb, he_emb);
  k3_gemm_mfma<<<(TT*EE)/64, 256, 0, stream>>>(he_emb, node, Bbf, b1, w2, esc, C_pe);
  k456<<<(VV*16)/256, 256, 0, stream>>>(ve, esc, C_pe, np_buf, Whh_m, bih_m, bhh_m,
                                        ain, aout, fcw, fcb, (float*)d_out);
}

// Round 6
// 232.679 us; speedup vs baseline: 4.3193x; 1.0752x over previous
//
#include <hip/hip_runtime.h>
#include <hip/hip_bf16.h>
#include <math.h>

// Problem constants
#define TT 4
#define VV 4096
#define EE 4096
#define KK 32
#define DD 8
#define HH 16
#define BERTD 768
#define CATD 784
#define NH 196      // CAT/4 hidden units of EdgeConv MLP
#define NTOT 260    // 196 hidden + 64 pe (Wih_m projection)
#define KPB 800     // K padded to 25*32
#define NPB 288     // N padded to 18*16 (6 chunks x 48)
#define LDB 808     // LDS row stride in halves for B chunk (bank-friendly)

typedef __bf16 bf16x8 __attribute__((ext_vector_type(8)));
typedef float  f32x4  __attribute__((ext_vector_type(4)));

__device__ __forceinline__ float sigmoidf_(float x){ return 1.0f/(1.0f+expf(-x)); }
__device__ __forceinline__ unsigned short f2bf(float f){
  __bf16 h = (__bf16)f;
  return __builtin_bit_cast(unsigned short, h);
}
__device__ __forceinline__ float bf2f(unsigned short u){
  unsigned int x = ((unsigned int)u) << 16;
  return __builtin_bit_cast(float, x);
}
__device__ __forceinline__ bf16x8 cvt_bf8(float4 a, float4 b){
  bf16x8 r;
  r[0]=(__bf16)a.x; r[1]=(__bf16)a.y; r[2]=(__bf16)a.z; r[3]=(__bf16)a.w;
  r[4]=(__bf16)b.x; r[5]=(__bf16)b.y; r[6]=(__bf16)b.z; r[7]=(__bf16)b.w;
  return r;
}

// ---------------------------------------------------------------------------
// kP: fused prep.
//  blocks [0,256):    price LSTM (16 lanes/vertex) -> np (T,V,16) f32
//  blocks [256,544):  pack [ec_w1 ; Wih_m] -> Bbf[288][800] bf16 (zero-pad)
//  blocks [544,546):  pack vc_trans_w -> twbf[32*32][16] bf16
//  blocks [546,562):  zero esc (16384 f32)
// ---------------------------------------------------------------------------
__global__ __launch_bounds__(256) void kP(
    const float* __restrict__ prices,
    const float* __restrict__ Wih, const float* __restrict__ Whh,
    const float* __restrict__ bih, const float* __restrict__ bhh,
    float* __restrict__ np_out,
    const float* __restrict__ w1, const float* __restrict__ wm,
    unsigned short* __restrict__ Bbf,
    const float* __restrict__ tw, unsigned short* __restrict__ twbf,
    float* __restrict__ esc){
  int b = blockIdx.x;
  int tid = threadIdx.x;
  if (b < 256){
    int lane = tid & 15;
    int v    = (b*256 + tid) >> 4;
    float W[4][16], wih[4], bb[4];
#pragma unroll
    for (int gi=0; gi<4; ++gi){
      int j = gi*16 + lane;
      const float4* wr = reinterpret_cast<const float4*>(&Whh[j*16]);
      float4 w0=wr[0], w1v=wr[1], w2v=wr[2], w3v=wr[3];
      W[gi][0]=w0.x; W[gi][1]=w0.y; W[gi][2]=w0.z; W[gi][3]=w0.w;
      W[gi][4]=w1v.x; W[gi][5]=w1v.y; W[gi][6]=w1v.z; W[gi][7]=w1v.w;
      W[gi][8]=w2v.x; W[gi][9]=w2v.y; W[gi][10]=w2v.z; W[gi][11]=w2v.w;
      W[gi][12]=w3v.x; W[gi][13]=w3v.y; W[gi][14]=w3v.z; W[gi][15]=w3v.w;
      wih[gi] = Wih[j];
      bb[gi]  = bih[j] + bhh[j];
    }
    float h = 0.f, c = 0.f;
    for (int t=0; t<TT; ++t){
      float x = prices[t*VV + v];
      float a0 = fmaf(x, wih[0], bb[0]);
      float a1 = fmaf(x, wih[1], bb[1]);
      float a2 = fmaf(x, wih[2], bb[2]);
      float a3 = fmaf(x, wih[3], bb[3]);
#pragma unroll
      for (int d=0; d<16; ++d){
        float hb = __shfl(h, d, 16);
        a0 = fmaf(hb, W[0][d], a0);
        a1 = fmaf(hb, W[1][d], a1);
        a2 = fmaf(hb, W[2][d], a2);
        a3 = fmaf(hb, W[3][d], a3);
      }
      float ig = sigmoidf_(a0);
      float fg = sigmoidf_(a1);
      float gg = tanhf(a2);
      float og = sigmoidf_(a3);
      c = fmaf(fg, c, ig*gg);
      h = og * tanhf(c);
      np_out[(size_t)(t*VV+v)*16 + lane] = h;
    }
  } else if (b < 544){
    int n = b - 256;
    const float* src = nullptr;
    if (n < NH)        src = &w1[(size_t)n*CATD];
    else if (n < NTOT) src = &wm[(size_t)(n-NH)*CATD];
    for (int kx = tid; kx < KPB; kx += 256){
      float v = (src != nullptr && kx < CATD) ? src[kx] : 0.f;
      Bbf[(size_t)n*KPB + kx] = f2bf(v);
    }
  } else if (b < 546){
    int base = (b - 544) * 512;
#pragma unroll
    for (int rr = 0; rr < 2; ++rr){
      int r = base + tid*2 + rr;
      const float* s = &tw[(size_t)r*16];
#pragma unroll
      for (int d = 0; d < 16; ++d) twbf[(size_t)r*16 + d] = f2bf(s[d]);
    }
  } else {
    int idx = ((b - 546)*256 + tid)*4;
    float4 z = make_float4(0.f,0.f,0.f,0.f);
    *reinterpret_cast<float4*>(&esc[idx]) = z;
  }
}

// ---------------------------------------------------------------------------
// K2: VertexConv via MFMA. Block = 16 hyperedges (te), 256 thr, 4 waves.
// ---------------------------------------------------------------------------
__global__ __launch_bounds__(256) void k2_fused(
    const float* __restrict__ np, const int* __restrict__ mem,
    const unsigned short* __restrict__ twbf, const float* __restrict__ tb,
    const float* __restrict__ cw, const float* __restrict__ cb,
    float* __restrict__ he_emb){
  __shared__ unsigned short s_reg[32*16*16];  // [k][te][d] bf16, 16 KB
  __shared__ float s_wsumP[4][16][32];        // per-wave partial wsum, 8 KB
  __shared__ int   s_mem[512];
  int tid = threadIdx.x;
  int te0 = blockIdx.x * 16;
  for (int i = tid; i < 512; i += 256) s_mem[i] = mem[(size_t)te0*32 + i];
  __syncthreads();
  for (int p = tid; p < 512; p += 256){
    int gte = p & 15, gk = p >> 4;
    int t   = (te0 + gte) >> 12;
    int vid = s_mem[gte*32 + gk];
    const float4* src = reinterpret_cast<const float4*>(&np[((size_t)(t*VV) + vid)*16]);
    float4 f0 = src[0], f1 = src[1], f2 = src[2], f3 = src[3];
    uint4 u0, u1;
    u0.x = (unsigned)f2bf(f0.x) | ((unsigned)f2bf(f0.y) << 16);
    u0.y = (unsigned)f2bf(f0.z) | ((unsigned)f2bf(f0.w) << 16);
    u0.z = (unsigned)f2bf(f1.x) | ((unsigned)f2bf(f1.y) << 16);
    u0.w = (unsigned)f2bf(f1.z) | ((unsigned)f2bf(f1.w) << 16);
    u1.x = (unsigned)f2bf(f2.x) | ((unsigned)f2bf(f2.y) << 16);
    u1.y = (unsigned)f2bf(f2.z) | ((unsigned)f2bf(f2.w) << 16);
    u1.z = (unsigned)f2bf(f3.x) | ((unsigned)f2bf(f3.y) << 16);
    u1.w = (unsigned)f2bf(f3.z) | ((unsigned)f2bf(f3.w) << 16);
    uint4* dst = reinterpret_cast<uint4*>(&s_reg[(gk*16 + gte)*16]);
    dst[0] = u0; dst[1] = u1;
  }
  __syncthreads();
  int l = tid & 63;
  int w = tid >> 6;
  int lj = l & 15;
  int lg = l >> 4;
  float w0acc[4] = {0.f,0.f,0.f,0.f};
  float w1acc[4] = {0.f,0.f,0.f,0.f};
#pragma unroll
  for (int kk = 0; kk < 8; ++kk){
    int k = w*8 + kk;
    bf16x8 af = 0, b0 = 0, b1v = 0;
    if (l < 32){
      af  = *reinterpret_cast<const bf16x8*>(&s_reg[(k*16 + lj)*16 + lg*8]);
      b0  = *reinterpret_cast<const bf16x8*>(&twbf[((size_t)k*32 + lj)*16 + lg*8]);
      b1v = *reinterpret_cast<const bf16x8*>(&twbf[((size_t)k*32 + 16 + lj)*16 + lg*8]);
    }
    float tb0 = tb[k*32 + lj];
    float tb1 = tb[k*32 + 16 + lj];
    f32x4 c0 = {tb0, tb0, tb0, tb0};
    f32x4 c1 = {tb1, tb1, tb1, tb1};
    f32x4 s0 = __builtin_amdgcn_mfma_f32_16x16x32_bf16(af, b0,  c0, 0, 0, 0);
    f32x4 s1 = __builtin_amdgcn_mfma_f32_16x16x32_bf16(af, b1v, c1, 0, 0, 0);
    float cwk = cw[k];
#pragma unroll
    for (int i = 0; i < 4; ++i){
      float v0 = s0[i], v1 = s1[i];
      float m = fmaxf(v0, v1);
#pragma unroll
      for (int off = 1; off < 16; off <<= 1) m = fmaxf(m, __shfl_xor(m, off, 16));
      float e0 = expf(v0 - m), e1 = expf(v1 - m);
      float sm = e0 + e1;
#pragma unroll
      for (int off = 1; off < 16; off <<= 1) sm += __shfl_xor(sm, off, 16);
      float f = cwk / sm;
      w0acc[i] = fmaf(e0, f, w0acc[i]);
      w1acc[i] = fmaf(e1, f, w1acc[i]);
    }
  }
#pragma unroll
  for (int i = 0; i < 4; ++i){
    int ter = lg*4 + i;
    s_wsumP[w][ter][lj]      = w0acc[i];
    s_wsumP[w][ter][16 + lj] = w1acc[i];
  }
  __syncthreads();
  int te = tid >> 4, d = tid & 15;
  float he = cb[0];
#pragma unroll
  for (int j = 0; j < 32; ++j){
    float ws = s_wsumP[0][te][j] + s_wsumP[1][te][j]
             + s_wsumP[2][te][j] + s_wsumP[3][te][j];
    he = fmaf(ws, bf2f(s_reg[(j*16 + te)*16 + d]), he);
  }
  he_emb[((size_t)(te0 + te))*16 + d] = he;
}

// ---------------------------------------------------------------------------
// K3: B-stationary bf16 MFMA GEMM. Grid (6 n-chunks, 128 m-blocks), 256 thr.
// B chunk (48 cols x 800 k) resident in LDS for whole kernel; one barrier.
// A streamed global->reg (f32 -> bf16 cvt in-register). Wave = 32 rows.
// Epilogue: hidden cols -> relu*w2 reduce -> atomicAdd esc; pe cols -> C_pe.
// ---------------------------------------------------------------------------
__global__ __launch_bounds__(256) void k3_gemm_mfma(
    const float* __restrict__ he_emb, const float* __restrict__ node,
    const unsigned short* __restrict__ Bbf, const float* __restrict__ b1,
    const float* __restrict__ w2, float* __restrict__ esc,
    float* __restrict__ C_pe){
  __shared__ unsigned short Bs[48*LDB];   // 77.5 KB
  int tid = threadIdx.x;
  int nc = blockIdx.x;     // 0..5
  int mb = blockIdx.y;     // 0..127
  for (int i = tid; i < 4800; i += 256){
    int r = i / 100, c = i - r*100;
    *reinterpret_cast<uint4*>(&Bs[r*LDB + c*8]) =
      *reinterpret_cast<const uint4*>(&Bbf[(size_t)(nc*48 + r)*KPB + c*8]);
  }
  __syncthreads();
  int l = tid & 63, w = tid >> 6;
  int lr = l & 15, ls = l >> 4;
  int m0 = mb*128 + w*32;
  int row0 = m0 + lr, row1 = m0 + 16 + lr;
  const unsigned short* bbase = &Bs[lr*LDB + ls*8];
  f32x4 acc[2][3] = {};
#pragma unroll
  for (int s = 0; s < 25; ++s){
    bf16x8 af0 = 0, af1 = 0;
    if (s == 0){
      if (ls < 2){
        const float4* p0 = reinterpret_cast<const float4*>(&he_emb[(size_t)row0*16 + ls*8]);
        const float4* p1 = reinterpret_cast<const float4*>(&he_emb[(size_t)row1*16 + ls*8]);
        af0 = cvt_bf8(p0[0], p0[1]);
        af1 = cvt_bf8(p1[0], p1[1]);
      } else {
        const float4* p0 = reinterpret_cast<const float4*>(&node[(size_t)row0*BERTD + ls*8 - 16]);
        const float4* p1 = reinterpret_cast<const float4*>(&node[(size_t)row1*BERTD + ls*8 - 16]);
        af0 = cvt_bf8(p0[0], p0[1]);
        af1 = cvt_bf8(p1[0], p1[1]);
      }
    } else if (!(s == 24 && ls >= 2)){
      int ko = s*32 + ls*8 - 16;
      const float4* p0 = reinterpret_cast<const float4*>(&node[(size_t)row0*BERTD + ko]);
      const float4* p1 = reinterpret_cast<const float4*>(&node[(size_t)row1*BERTD + ko]);
      af0 = cvt_bf8(p0[0], p0[1]);
      af1 = cvt_bf8(p1[0], p1[1]);
    }
#pragma unroll
    for (int j = 0; j < 3; ++j){
      bf16x8 bfv = *reinterpret_cast<const bf16x8*>(&bbase[j*16*LDB + s*32]);
      acc[0][j] = __builtin_amdgcn_mfma_f32_16x16x32_bf16(af0, bfv, acc[0][j], 0, 0, 0);
      acc[1][j] = __builtin_amdgcn_mfma_f32_16x16x32_bf16(af1, bfv, acc[1][j], 0, 0, 0);
    }
  }
  // epilogue
  float p[2][4] = {{0.f,0.f,0.f,0.f},{0.f,0.f,0.f,0.f}};
#pragma unroll
  for (int j = 0; j < 3; ++j){
    int n = nc*48 + j*16 + lr;
    bool hid = (n < NH);
    float b1n = hid ? b1[n] : 0.f;
    float w2n = hid ? w2[n] : 0.f;
#pragma unroll
    for (int i = 0; i < 2; ++i){
#pragma unroll
      for (int q = 0; q < 4; ++q){
        float v = acc[i][j][q];
        if (hid){
          p[i][q] += fmaxf(v + b1n, 0.f) * w2n;
        } else if (n < NTOT){
          int m = m0 + i*16 + ls*4 + q;
          C_pe[(size_t)m*64 + (n - NH)] = v;
        }
      }
    }
  }
  if (nc*48 < NH){
#pragma unroll
    for (int i = 0; i < 2; ++i){
#pragma unroll
      for (int q = 0; q < 4; ++q){
        float v = p[i][q];
#pragma unroll
        for (int off = 1; off < 16; off <<= 1) v += __shfl_xor(v, off, 16);
        if (lr == 0){
          int m = m0 + i*16 + ls*4 + q;
          atomicAdd(&esc[m], v);
        }
      }
    }
  }
}

// ---------------------------------------------------------------------------
// K456: fused edge-gather + LSTM2 + attention + FC. 16 lanes per vertex.
// ---------------------------------------------------------------------------
__global__ __launch_bounds__(256) void k456(
    const int* __restrict__ ve, const float* __restrict__ esc,
    const float* __restrict__ C_pe, const float* __restrict__ np,
    const float* __restrict__ Whh, const float* __restrict__ bih,
    const float* __restrict__ bhh,
    const float* __restrict__ ain, const float* __restrict__ aout,
    const float* __restrict__ fcw, const float* __restrict__ fcb,
    float* __restrict__ out){
  __shared__ float s_ain[16*17];
  __shared__ float s_aout[16*33];
  __shared__ float s_fc[32];
  __shared__ float s_fcb[2];
  int tid = threadIdx.x;
  { int j = tid >> 4, d = tid & 15; s_ain[j*17+d] = ain[tid]; }
  for (int i = tid; i < 512; i += 256){ int j = i >> 5, d = i & 31; s_aout[j*33+d] = aout[i]; }
  if (tid < 32) s_fc[tid] = fcw[tid];
  if (tid < 2)  s_fcb[tid] = fcb[tid];
  int lane = tid & 15;
  int v = (blockIdx.x*256 + tid) >> 4;
  float W[4][16], b[4];
#pragma unroll
  for (int gi=0; gi<4; ++gi){
    int j = gi*16 + lane;
    const float4* wr = reinterpret_cast<const float4*>(&Whh[j*16]);
    float4 w0=wr[0], w1=wr[1], w2=wr[2], w3=wr[3];
    W[gi][0]=w0.x; W[gi][1]=w0.y; W[gi][2]=w0.z; W[gi][3]=w0.w;
    W[gi][4]=w1.x; W[gi][5]=w1.y; W[gi][6]=w1.z; W[gi][7]=w1.w;
    W[gi][8]=w2.x; W[gi][9]=w2.y; W[gi][10]=w2.z; W[gi][11]=w2.w;
    W[gi][12]=w3.x; W[gi][13]=w3.y; W[gi][14]=w3.z; W[gi][15]=w3.w;
    b[gi] = bih[j] + bhh[j];
  }
  __syncthreads();
  float h = 0.f, c = 0.f;
  float la0, la1, la2, la3;
#pragma unroll
  for (int t=0; t<TT; ++t){
    const int* vp = &ve[((size_t)(t*VV) + v)*8];
    int e[8]; float wv[8];
    float mx = -1e30f;
#pragma unroll
    for (int d = 0; d < 8; ++d){
      e[d] = vp[d];
      wv[d] = esc[(t << 12) + e[d]];
      mx = fmaxf(mx, wv[d]);
    }
    float s = 0.f;
#pragma unroll
    for (int d = 0; d < 8; ++d){ wv[d] = expf(wv[d]-mx); s += wv[d]; }
    float inv = 1.f/s;
#pragma unroll
    for (int d = 0; d < 8; ++d) wv[d] *= inv;
    float g0 = b[0], g1 = b[1], g2 = b[2], g3 = b[3];
#pragma unroll
    for (int d = 0; d < 8; ++d){
      const float* cp = &C_pe[(size_t)((t << 12) + e[d])*64];
      g0 = fmaf(wv[d], cp[lane],      g0);
      g1 = fmaf(wv[d], cp[16 + lane], g1);
      g2 = fmaf(wv[d], cp[32 + lane], g2);
      g3 = fmaf(wv[d], cp[48 + lane], g3);
    }
#pragma unroll
    for (int d=0; d<16; ++d){
      float hb = __shfl(h, d, 16);
      g0 = fmaf(hb, W[0][d], g0);
      g1 = fmaf(hb, W[1][d], g1);
      g2 = fmaf(hb, W[2][d], g2);
      g3 = fmaf(hb, W[3][d], g3);
    }
    float ig = sigmoidf_(g0);
    float fg = sigmoidf_(g1);
    float gg = tanhf(g2);
    float og = sigmoidf_(g3);
    c = fmaf(fg, c, ig*gg);
    h = og * tanhf(c);
    float la = h + np[(size_t)(t*VV+v)*16 + lane];
    if (t == 0) la0 = la; else if (t == 1) la1 = la;
    else if (t == 2) la2 = la; else la3 = la;
  }
  float q = 0.f;
#pragma unroll
  for (int d=0; d<16; ++d){
    float bb = __shfl(la3, d, 16);
    q = fmaf(bb, s_ain[lane*17+d], q);
  }
  float aw0 = q*la0, aw1 = q*la1, aw2 = q*la2, aw3 = q*la3;
#pragma unroll
  for (int off=1; off<16; off<<=1){
    aw0 += __shfl_xor(aw0, off, 16);
    aw1 += __shfl_xor(aw1, off, 16);
    aw2 += __shfl_xor(aw2, off, 16);
    aw3 += __shfl_xor(aw3, off, 16);
  }
  float mx = fmaxf(fmaxf(aw0,aw1), fmaxf(aw2,aw3));
  aw0 = expf(aw0-mx); aw1 = expf(aw1-mx); aw2 = expf(aw2-mx); aw3 = expf(aw3-mx);
  float inv = 1.f/(aw0+aw1+aw2+aw3);
  float mix = (aw0*la0 + aw1*la1 + aw2*la2 + aw3*la3) * inv;
  float a = 0.f;
#pragma unroll
  for (int d=0; d<16; ++d){
    float m  = __shfl(mix, d, 16);
    float qq = __shfl(q,  d, 16);
    a = fmaf(m,  s_aout[lane*33+d],    a);
    a = fmaf(qq, s_aout[lane*33+16+d], a);
  }
  float at = tanhf(a);
  float p0 = at * s_fc[lane];
  float p1 = at * s_fc[16+lane];
#pragma unroll
  for (int off=1; off<16; off<<=1){
    p0 += __shfl_xor(p0, off, 16);
    p1 += __shfl_xor(p1, off, 16);
  }
  if (lane == 0){
    out[(size_t)v*2 + 0] = p0 + s_fcb[0];
    out[(size_t)v*2 + 1] = p1 + s_fcb[1];
  }
}

// ---------------------------------------------------------------------------
extern "C" void kernel_launch(void* const* d_in, const int* in_sizes, int n_in,
                              void* d_out, int out_size, void* d_ws, size_t ws_size,
                              hipStream_t stream){
  const float* prices = (const float*)d_in[0];
  const float* node   = (const float*)d_in[1];
  const int*   mem    = (const int*)d_in[2];
  const int*   ve     = (const int*)d_in[3];
  const float* Wih_p  = (const float*)d_in[4];
  const float* Whh_p  = (const float*)d_in[5];
  const float* bih_p  = (const float*)d_in[6];
  const float* bhh_p  = (const float*)d_in[7];
  const float* Wih_m  = (const float*)d_in[8];
  const float* Whh_m  = (const float*)d_in[9];
  const float* bih_m  = (const float*)d_in[10];
  const float* bhh_m  = (const float*)d_in[11];
  const float* tw     = (const float*)d_in[12];
  const float* tb     = (const float*)d_in[13];
  const float* cw     = (const float*)d_in[14];
  const float* cb     = (const float*)d_in[15];
  const float* w1     = (const float*)d_in[16];
  const float* b1     = (const float*)d_in[17];
  const float* w2     = (const float*)d_in[18];
  // d_in[19] = ec_b2: cancels in softmax, unused
  const float* ain    = (const float*)d_in[20];
  const float* aout   = (const float*)d_in[21];
  const float* fcw    = (const float*)d_in[22];
  const float* fcb    = (const float*)d_in[23];

  // workspace layout
  float* np_buf = (float*)d_ws;                       // T*V*16      = 262144 f
  float* he_emb = np_buf + (size_t)TT*VV*HH;          // T*E*16      = 262144 f
  float* esc    = he_emb + (size_t)TT*EE*HH;          // T*E         = 16384 f
  float* C_pe   = esc    + (size_t)TT*EE;             // 16384*64    = 1048576 f
  unsigned short* Bbf  = (unsigned short*)(C_pe + (size_t)TT*EE*64); // 288*800 u16
  unsigned short* twbf = Bbf + (size_t)NPB*KPB;                      // 1024*16 u16

  kP<<<562, 256, 0, stream>>>(prices, Wih_p, Whh_p, bih_p, bhh_p, np_buf,
                              w1, Wih_m, Bbf, tw, twbf, esc);
  k2_fused<<<(TT*EE)/16, 256, 0, stream>>>(np_buf, mem, twbf, tb, cw, cb, he_emb);
  k3_gemm_mfma<<<dim3(6, 128), 256, 0, stream>>>(he_emb, node, Bbf, b1, w2, esc, C_pe);
  k456<<<(VV*16)/256, 256, 0, stream>>>(ve, esc, C_pe, np_buf, Whh_m, bih_m, bhh_m,
                                        ain, aout, fcw, fcb, (float*)d_out);
}

// Round 7
// 211.914 us; speedup vs baseline: 4.7425x; 1.0980x over previous
//
#include <hip/hip_runtime.h>
#include <hip/hip_bf16.h>
#include <math.h>

// Problem constants
#define TT 4
#define VV 4096
#define EE 4096
#define KK 32
#define DD 8
#define HH 16
#define BERTD 768
#define CATD 784
#define NH 196      // CAT/4 hidden units of EdgeConv MLP
#define NTOT 260    // 196 hidden + 64 pe (Wih_m projection)
#define KPB 800     // K padded to 25*32
#define NPB 288     // N padded to 18*16 (6 chunks x 48)
#define LDB 808     // LDS row stride in halves for B chunk (bank-friendly)

typedef __bf16 bf16x8 __attribute__((ext_vector_type(8)));
typedef float  f32x4  __attribute__((ext_vector_type(4)));

__device__ __forceinline__ float sigmoidf_(float x){ return 1.0f/(1.0f+expf(-x)); }
__device__ __forceinline__ unsigned short f2bf(float f){
  __bf16 h = (__bf16)f;
  return __builtin_bit_cast(unsigned short, h);
}
__device__ __forceinline__ float bf2f(unsigned short u){
  unsigned int x = ((unsigned int)u) << 16;
  return __builtin_bit_cast(float, x);
}
__device__ __forceinline__ uint4 pack8(float4 a, float4 b){
  uint4 u;
  u.x = (unsigned)f2bf(a.x) | ((unsigned)f2bf(a.y) << 16);
  u.y = (unsigned)f2bf(a.z) | ((unsigned)f2bf(a.w) << 16);
  u.z = (unsigned)f2bf(b.x) | ((unsigned)f2bf(b.y) << 16);
  u.w = (unsigned)f2bf(b.z) | ((unsigned)f2bf(b.w) << 16);
  return u;
}

// ---------------------------------------------------------------------------
// kP: fused prep.
//  blocks [0,256):     price LSTM (16 lanes/vertex) -> np (T,V,16) f32
//  blocks [256,544):   pack [ec_w1 ; Wih_m] -> Bbf[288][800] bf16 (zero-pad)
//  blocks [544,546):   pack vc_trans_w -> twbf[32*32][16] bf16
//  blocks [546,562):   zero esc (16384 f32)
//  blocks [562,1586):  pack node_embs -> Abf[.][16..783] bf16, zero 784..799
// ---------------------------------------------------------------------------
__global__ __launch_bounds__(256) void kP(
    const float* __restrict__ prices,
    const float* __restrict__ Wih, const float* __restrict__ Whh,
    const float* __restrict__ bih, const float* __restrict__ bhh,
    float* __restrict__ np_out,
    const float* __restrict__ w1, const float* __restrict__ wm,
    unsigned short* __restrict__ Bbf,
    const float* __restrict__ tw, unsigned short* __restrict__ twbf,
    float* __restrict__ esc,
    const float* __restrict__ node, unsigned short* __restrict__ Abf){
  int b = blockIdx.x;
  int tid = threadIdx.x;
  if (b < 256){
    int lane = tid & 15;
    int v    = (b*256 + tid) >> 4;
    float W[4][16], wih[4], bb[4];
#pragma unroll
    for (int gi=0; gi<4; ++gi){
      int j = gi*16 + lane;
      const float4* wr = reinterpret_cast<const float4*>(&Whh[j*16]);
      float4 w0=wr[0], w1v=wr[1], w2v=wr[2], w3v=wr[3];
      W[gi][0]=w0.x; W[gi][1]=w0.y; W[gi][2]=w0.z; W[gi][3]=w0.w;
      W[gi][4]=w1v.x; W[gi][5]=w1v.y; W[gi][6]=w1v.z; W[gi][7]=w1v.w;
      W[gi][8]=w2v.x; W[gi][9]=w2v.y; W[gi][10]=w2v.z; W[gi][11]=w2v.w;
      W[gi][12]=w3v.x; W[gi][13]=w3v.y; W[gi][14]=w3v.z; W[gi][15]=w3v.w;
      wih[gi] = Wih[j];
      bb[gi]  = bih[j] + bhh[j];
    }
    float h = 0.f, c = 0.f;
    for (int t=0; t<TT; ++t){
      float x = prices[t*VV + v];
      float a0 = fmaf(x, wih[0], bb[0]);
      float a1 = fmaf(x, wih[1], bb[1]);
      float a2 = fmaf(x, wih[2], bb[2]);
      float a3 = fmaf(x, wih[3], bb[3]);
#pragma unroll
      for (int d=0; d<16; ++d){
        float hb = __shfl(h, d, 16);
        a0 = fmaf(hb, W[0][d], a0);
        a1 = fmaf(hb, W[1][d], a1);
        a2 = fmaf(hb, W[2][d], a2);
        a3 = fmaf(hb, W[3][d], a3);
      }
      float ig = sigmoidf_(a0);
      float fg = sigmoidf_(a1);
      float gg = tanhf(a2);
      float og = sigmoidf_(a3);
      c = fmaf(fg, c, ig*gg);
      h = og * tanhf(c);
      np_out[(size_t)(t*VV+v)*16 + lane] = h;
    }
  } else if (b < 544){
    int n = b - 256;
    const float* src = nullptr;
    if (n < NH)        src = &w1[(size_t)n*CATD];
    else if (n < NTOT) src = &wm[(size_t)(n-NH)*CATD];
    for (int kx = tid; kx < KPB; kx += 256){
      float v = (src != nullptr && kx < CATD) ? src[kx] : 0.f;
      Bbf[(size_t)n*KPB + kx] = f2bf(v);
    }
  } else if (b < 546){
    int base = (b - 544) * 512;
#pragma unroll
    for (int rr = 0; rr < 2; ++rr){
      int r = base + tid*2 + rr;
      const float* s = &tw[(size_t)r*16];
#pragma unroll
      for (int d = 0; d < 16; ++d) twbf[(size_t)r*16 + d] = f2bf(s[d]);
    }
  } else if (b < 562){
    int idx = ((b - 546)*256 + tid)*4;
    float4 z = make_float4(0.f,0.f,0.f,0.f);
    *reinterpret_cast<float4*>(&esc[idx]) = z;
  } else {
    // node pack: 16 rows per block; thread (row = tid>>4, seg = tid&15)
    int row = (b - 562)*16 + (tid >> 4);
    int c0  = (tid & 15) * 48;
    const float* src = &node[(size_t)row*BERTD + c0];
    unsigned short* dst = &Abf[(size_t)row*KPB + 16 + c0];
#pragma unroll
    for (int cc = 0; cc < 6; ++cc){
      float4 f0 = *reinterpret_cast<const float4*>(&src[cc*8]);
      float4 f1 = *reinterpret_cast<const float4*>(&src[cc*8+4]);
      *reinterpret_cast<uint4*>(&dst[cc*8]) = pack8(f0, f1);
    }
    if ((tid & 15) == 15){
      uint4 z = {0,0,0,0};
      unsigned short* zp = &Abf[(size_t)row*KPB + 784];
      *reinterpret_cast<uint4*>(&zp[0]) = z;
      *reinterpret_cast<uint4*>(&zp[8]) = z;
    }
  }
}

// ---------------------------------------------------------------------------
// K2: VertexConv via MFMA. Block = 16 hyperedges (te), 256 thr, 4 waves.
// Writes he_emb as bf16 directly into Abf[.][0..15].
// ---------------------------------------------------------------------------
__global__ __launch_bounds__(256) void k2_fused(
    const float* __restrict__ np, const int* __restrict__ mem,
    const unsigned short* __restrict__ twbf, const float* __restrict__ tb,
    const float* __restrict__ cw, const float* __restrict__ cb,
    unsigned short* __restrict__ Abf){
  __shared__ unsigned short s_reg[32*16*16];  // [k][te][d] bf16, 16 KB
  __shared__ float s_wsumP[4][16][32];        // per-wave partial wsum, 8 KB
  __shared__ int   s_mem[512];
  int tid = threadIdx.x;
  int te0 = blockIdx.x * 16;
  for (int i = tid; i < 512; i += 256) s_mem[i] = mem[(size_t)te0*32 + i];
  __syncthreads();
  for (int p = tid; p < 512; p += 256){
    int gte = p & 15, gk = p >> 4;
    int t   = (te0 + gte) >> 12;
    int vid = s_mem[gte*32 + gk];
    const float4* src = reinterpret_cast<const float4*>(&np[((size_t)(t*VV) + vid)*16]);
    float4 f0 = src[0], f1 = src[1], f2 = src[2], f3 = src[3];
    uint4* dst = reinterpret_cast<uint4*>(&s_reg[(gk*16 + gte)*16]);
    dst[0] = pack8(f0, f1);
    dst[1] = pack8(f2, f3);
  }
  __syncthreads();
  int l = tid & 63;
  int w = tid >> 6;
  int lj = l & 15;
  int lg = l >> 4;
  float w0acc[4] = {0.f,0.f,0.f,0.f};
  float w1acc[4] = {0.f,0.f,0.f,0.f};
#pragma unroll
  for (int kk = 0; kk < 8; ++kk){
    int k = w*8 + kk;
    bf16x8 af = 0, b0 = 0, b1v = 0;
    if (l < 32){
      af  = *reinterpret_cast<const bf16x8*>(&s_reg[(k*16 + lj)*16 + lg*8]);
      b0  = *reinterpret_cast<const bf16x8*>(&twbf[((size_t)k*32 + lj)*16 + lg*8]);
      b1v = *reinterpret_cast<const bf16x8*>(&twbf[((size_t)k*32 + 16 + lj)*16 + lg*8]);
    }
    float tb0 = tb[k*32 + lj];
    float tb1 = tb[k*32 + 16 + lj];
    f32x4 c0 = {tb0, tb0, tb0, tb0};
    f32x4 c1 = {tb1, tb1, tb1, tb1};
    f32x4 s0 = __builtin_amdgcn_mfma_f32_16x16x32_bf16(af, b0,  c0, 0, 0, 0);
    f32x4 s1 = __builtin_amdgcn_mfma_f32_16x16x32_bf16(af, b1v, c1, 0, 0, 0);
    float cwk = cw[k];
#pragma unroll
    for (int i = 0; i < 4; ++i){
      float v0 = s0[i], v1 = s1[i];
      float m = fmaxf(v0, v1);
#pragma unroll
      for (int off = 1; off < 16; off <<= 1) m = fmaxf(m, __shfl_xor(m, off, 16));
      float e0 = expf(v0 - m), e1 = expf(v1 - m);
      float sm = e0 + e1;
#pragma unroll
      for (int off = 1; off < 16; off <<= 1) sm += __shfl_xor(sm, off, 16);
      float f = cwk / sm;
      w0acc[i] = fmaf(e0, f, w0acc[i]);
      w1acc[i] = fmaf(e1, f, w1acc[i]);
    }
  }
#pragma unroll
  for (int i = 0; i < 4; ++i){
    int ter = lg*4 + i;
    s_wsumP[w][ter][lj]      = w0acc[i];
    s_wsumP[w][ter][16 + lj] = w1acc[i];
  }
  __syncthreads();
  int te = tid >> 4, d = tid & 15;
  float he = cb[0];
#pragma unroll
  for (int j = 0; j < 32; ++j){
    float ws = s_wsumP[0][te][j] + s_wsumP[1][te][j]
             + s_wsumP[2][te][j] + s_wsumP[3][te][j];
    he = fmaf(ws, bf2f(s_reg[(j*16 + te)*16 + d]), he);
  }
  Abf[((size_t)(te0 + te))*KPB + d] = f2bf(he);
}

// ---------------------------------------------------------------------------
// K3: B-stationary bf16 MFMA GEMM, XCD-affinity swizzle.
// Grid 768 linear: bid = group*48 + nc*8 + mbr -> all 6 n-chunks of an
// m-panel share bid%8 (same XCD L2). B chunk (48 x 800) LDS-resident; one
// barrier; A read as bf16 fragments (one 16B load per frag per step).
// ---------------------------------------------------------------------------
__global__ __launch_bounds__(256) void k3_gemm_mfma(
    const unsigned short* __restrict__ Abf,
    const unsigned short* __restrict__ Bbf, const float* __restrict__ b1,
    const float* __restrict__ w2, float* __restrict__ esc,
    float* __restrict__ C_pe){
  __shared__ unsigned short Bs[48*LDB];   // 77.6 KB
  int tid = threadIdx.x;
  int bid = blockIdx.x;
  int group = bid / 48;
  int within = bid - group*48;
  int nc  = within >> 3;        // 0..5
  int mbr = within & 7;
  int mb  = group*8 + mbr;      // 0..127
  for (int i = tid; i < 4800; i += 256){
    int r = i / 100, c = i - r*100;
    *reinterpret_cast<uint4*>(&Bs[r*LDB + c*8]) =
      *reinterpret_cast<const uint4*>(&Bbf[(size_t)(nc*48 + r)*KPB + c*8]);
  }
  __syncthreads();
  int l = tid & 63, w = tid >> 6;
  int lr = l & 15, ls = l >> 4;
  int m0 = mb*128 + w*32;
  const unsigned short* a0p = &Abf[(size_t)(m0 + lr)*KPB];
  const unsigned short* a1p = a0p + (size_t)16*KPB;
  const unsigned short* bbase = &Bs[lr*LDB + ls*8];
  f32x4 acc[2][3] = {};
#pragma unroll
  for (int s = 0; s < 25; ++s){
    bf16x8 af0 = *reinterpret_cast<const bf16x8*>(&a0p[s*32 + ls*8]);
    bf16x8 af1 = *reinterpret_cast<const bf16x8*>(&a1p[s*32 + ls*8]);
#pragma unroll
    for (int j = 0; j < 3; ++j){
      bf16x8 bfv = *reinterpret_cast<const bf16x8*>(&bbase[j*16*LDB + s*32]);
      acc[0][j] = __builtin_amdgcn_mfma_f32_16x16x32_bf16(af0, bfv, acc[0][j], 0, 0, 0);
      acc[1][j] = __builtin_amdgcn_mfma_f32_16x16x32_bf16(af1, bfv, acc[1][j], 0, 0, 0);
    }
  }
  // epilogue
  float p[2][4] = {{0.f,0.f,0.f,0.f},{0.f,0.f,0.f,0.f}};
#pragma unroll
  for (int j = 0; j < 3; ++j){
    int n = nc*48 + j*16 + lr;
    bool hid = (n < NH);
    float b1n = hid ? b1[n] : 0.f;
    float w2n = hid ? w2[n] : 0.f;
#pragma unroll
    for (int i = 0; i < 2; ++i){
#pragma unroll
      for (int q = 0; q < 4; ++q){
        float v = acc[i][j][q];
        if (hid){
          p[i][q] += fmaxf(v + b1n, 0.f) * w2n;
        } else if (n < NTOT){
          int m = m0 + i*16 + ls*4 + q;
          C_pe[(size_t)m*64 + (n - NH)] = v;
        }
      }
    }
  }
  if (nc*48 < NH){
#pragma unroll
    for (int i = 0; i < 2; ++i){
#pragma unroll
      for (int q = 0; q < 4; ++q){
        float v = p[i][q];
#pragma unroll
        for (int off = 1; off < 16; off <<= 1) v += __shfl_xor(v, off, 16);
        if (lr == 0){
          int m = m0 + i*16 + ls*4 + q;
          atomicAdd(&esc[m], v);
        }
      }
    }
  }
}

// ---------------------------------------------------------------------------
// K456: fused edge-gather + LSTM2 + attention + FC. 16 lanes per vertex.
// ---------------------------------------------------------------------------
__global__ __launch_bounds__(256) void k456(
    const int* __restrict__ ve, const float* __restrict__ esc,
    const float* __restrict__ C_pe, const float* __restrict__ np,
    const float* __restrict__ Whh, const float* __restrict__ bih,
    const float* __restrict__ bhh,
    const float* __restrict__ ain, const float* __restrict__ aout,
    const float* __restrict__ fcw, const float* __restrict__ fcb,
    float* __restrict__ out){
  __shared__ float s_ain[16*17];
  __shared__ float s_aout[16*33];
  __shared__ float s_fc[32];
  __shared__ float s_fcb[2];
  int tid = threadIdx.x;
  { int j = tid >> 4, d = tid & 15; s_ain[j*17+d] = ain[tid]; }
  for (int i = tid; i < 512; i += 256){ int j = i >> 5, d = i & 31; s_aout[j*33+d] = aout[i]; }
  if (tid < 32) s_fc[tid] = fcw[tid];
  if (tid < 2)  s_fcb[tid] = fcb[tid];
  int lane = tid & 15;
  int v = (blockIdx.x*256 + tid) >> 4;
  float W[4][16], b[4];
#pragma unroll
  for (int gi=0; gi<4; ++gi){
    int j = gi*16 + lane;
    const float4* wr = reinterpret_cast<const float4*>(&Whh[j*16]);
    float4 w0=wr[0], w1=wr[1], w2=wr[2], w3=wr[3];
    W[gi][0]=w0.x; W[gi][1]=w0.y; W[gi][2]=w0.z; W[gi][3]=w0.w;
    W[gi][4]=w1.x; W[gi][5]=w1.y; W[gi][6]=w1.z; W[gi][7]=w1.w;
    W[gi][8]=w2.x; W[gi][9]=w2.y; W[gi][10]=w2.z; W[gi][11]=w2.w;
    W[gi][12]=w3.x; W[gi][13]=w3.y; W[gi][14]=w3.z; W[gi][15]=w3.w;
    b[gi] = bih[j] + bhh[j];
  }
  __syncthreads();
  float h = 0.f, c = 0.f;
  float la0, la1, la2, la3;
#pragma unroll
  for (int t=0; t<TT; ++t){
    const int* vp = &ve[((size_t)(t*VV) + v)*8];
    int e[8]; float wv[8];
    float mx = -1e30f;
#pragma unroll
    for (int d = 0; d < 8; ++d){
      e[d] = vp[d];
      wv[d] = esc[(t << 12) + e[d]];
      mx = fmaxf(mx, wv[d]);
    }
    float s = 0.f;
#pragma unroll
    for (int d = 0; d < 8; ++d){ wv[d] = expf(wv[d]-mx); s += wv[d]; }
    float inv = 1.f/s;
#pragma unroll
    for (int d = 0; d < 8; ++d) wv[d] *= inv;
    float g0 = b[0], g1 = b[1], g2 = b[2], g3 = b[3];
#pragma unroll
    for (int d = 0; d < 8; ++d){
      const float* cp = &C_pe[(size_t)((t << 12) + e[d])*64];
      g0 = fmaf(wv[d], cp[lane],      g0);
      g1 = fmaf(wv[d], cp[16 + lane], g1);
      g2 = fmaf(wv[d], cp[32 + lane], g2);
      g3 = fmaf(wv[d], cp[48 + lane], g3);
    }
#pragma unroll
    for (int d=0; d<16; ++d){
      float hb = __shfl(h, d, 16);
      g0 = fmaf(hb, W[0][d], g0);
      g1 = fmaf(hb, W[1][d], g1);
      g2 = fmaf(hb, W[2][d], g2);
      g3 = fmaf(hb, W[3][d], g3);
    }
    float ig = sigmoidf_(g0);
    float fg = sigmoidf_(g1);
    float gg = tanhf(g2);
    float og = sigmoidf_(g3);
    c = fmaf(fg, c, ig*gg);
    h = og * tanhf(c);
    float la = h + np[(size_t)(t*VV+v)*16 + lane];
    if (t == 0) la0 = la; else if (t == 1) la1 = la;
    else if (t == 2) la2 = la; else la3 = la;
  }
  float q = 0.f;
#pragma unroll
  for (int d=0; d<16; ++d){
    float bb = __shfl(la3, d, 16);
    q = fmaf(bb, s_ain[lane*17+d], q);
  }
  float aw0 = q*la0, aw1 = q*la1, aw2 = q*la2, aw3 = q*la3;
#pragma unroll
  for (int off=1; off<16; off<<=1){
    aw0 += __shfl_xor(aw0, off, 16);
    aw1 += __shfl_xor(aw1, off, 16);
    aw2 += __shfl_xor(aw2, off, 16);
    aw3 += __shfl_xor(aw3, off, 16);
  }
  float mx = fmaxf(fmaxf(aw0,aw1), fmaxf(aw2,aw3));
  aw0 = expf(aw0-mx); aw1 = expf(aw1-mx); aw2 = expf(aw2-mx); aw3 = expf(aw3-mx);
  float inv = 1.f/(aw0+aw1+aw2+aw3);
  float mix = (aw0*la0 + aw1*la1 + aw2*la2 + aw3*la3) * inv;
  float a = 0.f;
#pragma unroll
  for (int d=0; d<16; ++d){
    float m  = __shfl(mix, d, 16);
    float qq = __shfl(q,  d, 16);
    a = fmaf(m,  s_aout[lane*33+d],    a);
    a = fmaf(qq, s_aout[lane*33+16+d], a);
  }
  float at = tanhf(a);
  float p0 = at * s_fc[lane];
  float p1 = at * s_fc[16+lane];
#pragma unroll
  for (int off=1; off<16; off<<=1){
    p0 += __shfl_xor(p0, off, 16);
    p1 += __shfl_xor(p1, off, 16);
  }
  if (lane == 0){
    out[(size_t)v*2 + 0] = p0 + s_fcb[0];
    out[(size_t)v*2 + 1] = p1 + s_fcb[1];
  }
}

// ---------------------------------------------------------------------------
extern "C" void kernel_launch(void* const* d_in, const int* in_sizes, int n_in,
                              void* d_out, int out_size, void* d_ws, size_t ws_size,
                              hipStream_t stream){
  const float* prices = (const float*)d_in[0];
  const float* node   = (const float*)d_in[1];
  const int*   mem    = (const int*)d_in[2];
  const int*   ve     = (const int*)d_in[3];
  const float* Wih_p  = (const float*)d_in[4];
  const float* Whh_p  = (const float*)d_in[5];
  const float* bih_p  = (const float*)d_in[6];
  const float* bhh_p  = (const float*)d_in[7];
  const float* Wih_m  = (const float*)d_in[8];
  const float* Whh_m  = (const float*)d_in[9];
  const float* bih_m  = (const float*)d_in[10];
  const float* bhh_m  = (const float*)d_in[11];
  const float* tw     = (const float*)d_in[12];
  const float* tb     = (const float*)d_in[13];
  const float* cw     = (const float*)d_in[14];
  const float* cb     = (const float*)d_in[15];
  const float* w1     = (const float*)d_in[16];
  const float* b1     = (const float*)d_in[17];
  const float* w2     = (const float*)d_in[18];
  // d_in[19] = ec_b2: cancels in softmax, unused
  const float* ain    = (const float*)d_in[20];
  const float* aout   = (const float*)d_in[21];
  const float* fcw    = (const float*)d_in[22];
  const float* fcb    = (const float*)d_in[23];

  // workspace layout
  float* np_buf = (float*)d_ws;                       // T*V*16   = 262144 f
  float* esc    = np_buf + (size_t)TT*VV*HH;          // T*E      = 16384 f
  float* C_pe   = esc    + (size_t)TT*EE;             // 16384*64 = 1048576 f
  unsigned short* Bbf  = (unsigned short*)(C_pe + (size_t)TT*EE*64); // 288*800 u16
  unsigned short* twbf = Bbf + (size_t)NPB*KPB;                      // 1024*16 u16
  unsigned short* Abf  = twbf + (size_t)1024*16;                     // 16384*800 u16

  kP<<<1586, 256, 0, stream>>>(prices, Wih_p, Whh_p, bih_p, bhh_p, np_buf,
                               w1, Wih_m, Bbf, tw, twbf, esc, node, Abf);
  k2_fused<<<(TT*EE)/16, 256, 0, stream>>>(np_buf, mem, twbf, tb, cw, cb, Abf);
  k3_gemm_mfma<<<768, 256, 0, stream>>>(Abf, Bbf, b1, w2, esc, C_pe);
  k456<<<(VV*16)/256, 256, 0, stream>>>(ve, esc, C_pe, np_buf, Whh_m, bih_m, bhh_m,
                                        ain, aout, fcw, fcb, (float*)d_out);
}

// Round 8
// 206.006 us; speedup vs baseline: 4.8785x; 1.0287x over previous
//
#include <hip/hip_runtime.h>
#include <hip/hip_bf16.h>
#include <math.h>

// Problem constants
#define TT 4
#define VV 4096
#define EE 4096
#define KK 32
#define DD 8
#define HH 16
#define BERTD 768
#define CATD 784
#define NH 196      // CAT/4 hidden units of EdgeConv MLP
#define NTOT 260    // 196 hidden + 64 pe (Wih_m projection)
#define NSTEP 25    // K steps of 32 (K padded to 800)
#define NPB 288     // N padded to 18*16 (6 chunks x 48)

typedef __bf16 bf16x8 __attribute__((ext_vector_type(8)));
typedef float  f32x4  __attribute__((ext_vector_type(4)));

__device__ __forceinline__ float sigmoidf_(float x){ return 1.0f/(1.0f+expf(-x)); }
__device__ __forceinline__ unsigned short f2bf(float f){
  __bf16 h = (__bf16)f;
  return __builtin_bit_cast(unsigned short, h);
}
__device__ __forceinline__ float bf2f(unsigned short u){
  unsigned int x = ((unsigned int)u) << 16;
  return __builtin_bit_cast(float, x);
}
__device__ __forceinline__ uint4 pack8(float4 a, float4 b){
  uint4 u;
  u.x = (unsigned)f2bf(a.x) | ((unsigned)f2bf(a.y) << 16);
  u.y = (unsigned)f2bf(a.z) | ((unsigned)f2bf(a.w) << 16);
  u.z = (unsigned)f2bf(b.x) | ((unsigned)f2bf(b.y) << 16);
  u.w = (unsigned)f2bf(b.z) | ((unsigned)f2bf(b.w) << 16);
  return u;
}

// Fragment-major A layout: Abf[((f16*25 + s)*64 + l)*8 + e]
//   <-> A[row = f16*16 + (l&15)][k = s*32 + (l>>4)*8 + e]
// Fragment-major B layout: Bbf[((n16*25 + s)*64 + l)*8 + e]
//   <-> B[n = n16*16 + (l&15)][k = s*32 + (l>>4)*8 + e]

// ---------------------------------------------------------------------------
// kP: fused prep.
//  blocks [0,1024):     pack node_embs -> Abf fragment-major (k>=16)
//  blocks [1024,1280):  price LSTM (16 lanes/vertex) -> np (T,V,16) f32
//  blocks [1280,1298):  pack [ec_w1 ; Wih_m] -> Bbf fragment-major
//  blocks [1298,1300):  pack vc_trans_w -> twbf[32*32][16] bf16
//  blocks [1300,1316):  zero esc (16384 f32)
// ---------------------------------------------------------------------------
__global__ __launch_bounds__(256) void kP(
    const float* __restrict__ prices,
    const float* __restrict__ Wih, const float* __restrict__ Whh,
    const float* __restrict__ bih, const float* __restrict__ bhh,
    float* __restrict__ np_out,
    const float* __restrict__ w1, const float* __restrict__ wm,
    unsigned short* __restrict__ Bbf,
    const float* __restrict__ tw, unsigned short* __restrict__ twbf,
    float* __restrict__ esc,
    const float* __restrict__ node, unsigned short* __restrict__ Abf){
  int b = blockIdx.x;
  int tid = threadIdx.x;
  if (b < 1024){
    int f16 = b;
    for (int i = tid; i < 1600; i += 256){
      int s = i >> 6, l = i & 63;
      int lr = l & 15, ls = l >> 4;
      int k = s*32 + ls*8;
      if (s == 0 && ls < 2) continue;            // k<16: he_emb, written by k2
      uint4* dst = reinterpret_cast<uint4*>(&Abf[((size_t)(f16*NSTEP + s)*64 + l)*8]);
      if (k >= CATD){
        uint4 z = {0,0,0,0};
        *dst = z;
      } else {
        int row = f16*16 + lr;
        const float* src = &node[(size_t)row*BERTD + (k - 16)];
        float4 f0 = *reinterpret_cast<const float4*>(&src[0]);
        float4 f1 = *reinterpret_cast<const float4*>(&src[4]);
        *dst = pack8(f0, f1);
      }
    }
  } else if (b < 1280){
    int bb2 = b - 1024;
    int lane = tid & 15;
    int v    = (bb2*256 + tid) >> 4;
    float W[4][16], wih[4], bb[4];
#pragma unroll
    for (int gi=0; gi<4; ++gi){
      int j = gi*16 + lane;
      const float4* wr = reinterpret_cast<const float4*>(&Whh[j*16]);
      float4 w0=wr[0], w1v=wr[1], w2v=wr[2], w3v=wr[3];
      W[gi][0]=w0.x; W[gi][1]=w0.y; W[gi][2]=w0.z; W[gi][3]=w0.w;
      W[gi][4]=w1v.x; W[gi][5]=w1v.y; W[gi][6]=w1v.z; W[gi][7]=w1v.w;
      W[gi][8]=w2v.x; W[gi][9]=w2v.y; W[gi][10]=w2v.z; W[gi][11]=w2v.w;
      W[gi][12]=w3v.x; W[gi][13]=w3v.y; W[gi][14]=w3v.z; W[gi][15]=w3v.w;
      wih[gi] = Wih[j];
      bb[gi]  = bih[j] + bhh[j];
    }
    float h = 0.f, c = 0.f;
    for (int t=0; t<TT; ++t){
      float x = prices[t*VV + v];
      float a0 = fmaf(x, wih[0], bb[0]);
      float a1 = fmaf(x, wih[1], bb[1]);
      float a2 = fmaf(x, wih[2], bb[2]);
      float a3 = fmaf(x, wih[3], bb[3]);
#pragma unroll
      for (int d=0; d<16; ++d){
        float hb = __shfl(h, d, 16);
        a0 = fmaf(hb, W[0][d], a0);
        a1 = fmaf(hb, W[1][d], a1);
        a2 = fmaf(hb, W[2][d], a2);
        a3 = fmaf(hb, W[3][d], a3);
      }
      float ig = sigmoidf_(a0);
      float fg = sigmoidf_(a1);
      float gg = tanhf(a2);
      float og = sigmoidf_(a3);
      c = fmaf(fg, c, ig*gg);
      h = og * tanhf(c);
      np_out[(size_t)(t*VV+v)*16 + lane] = h;
    }
  } else if (b < 1298){
    int n16 = b - 1280;
    for (int i = tid; i < 1600; i += 256){
      int s = i >> 6, l = i & 63;
      int lr = l & 15, ls = l >> 4;
      int n = n16*16 + lr;
      int k = s*32 + ls*8;
      uint4* dst = reinterpret_cast<uint4*>(&Bbf[((size_t)(n16*NSTEP + s)*64 + l)*8]);
      if (n < NTOT && k < CATD){
        const float* src = (n < NH) ? &w1[(size_t)n*CATD + k]
                                    : &wm[(size_t)(n-NH)*CATD + k];
        float4 f0 = *reinterpret_cast<const float4*>(&src[0]);
        float4 f1 = *reinterpret_cast<const float4*>(&src[4]);
        *dst = pack8(f0, f1);
      } else {
        uint4 z = {0,0,0,0};
        *dst = z;
      }
    }
  } else if (b < 1300){
    int base = (b - 1298) * 512;
#pragma unroll
    for (int rr = 0; rr < 2; ++rr){
      int r = base + tid*2 + rr;
      const float* s = &tw[(size_t)r*16];
#pragma unroll
      for (int d = 0; d < 16; ++d) twbf[(size_t)r*16 + d] = f2bf(s[d]);
    }
  } else {
    int idx = ((b - 1300)*256 + tid)*4;
    float4 z = make_float4(0.f,0.f,0.f,0.f);
    *reinterpret_cast<float4*>(&esc[idx]) = z;
  }
}

// ---------------------------------------------------------------------------
// K2: VertexConv via MFMA. Block = 16 hyperedges (te) = one f16 group.
// Writes he_emb bf16 into Abf fragment-major slots (s=0, k=0..15).
// ---------------------------------------------------------------------------
__global__ __launch_bounds__(256) void k2_fused(
    const float* __restrict__ np, const int* __restrict__ mem,
    const unsigned short* __restrict__ twbf, const float* __restrict__ tb,
    const float* __restrict__ cw, const float* __restrict__ cb,
    unsigned short* __restrict__ Abf){
  __shared__ unsigned short s_reg[32*16*16];  // [k][te][d] bf16, 16 KB
  __shared__ float s_wsumP[4][16][32];        // per-wave partial wsum, 8 KB
  __shared__ int   s_mem[512];
  int tid = threadIdx.x;
  int te0 = blockIdx.x * 16;
  for (int i = tid; i < 512; i += 256) s_mem[i] = mem[(size_t)te0*32 + i];
  __syncthreads();
  for (int p = tid; p < 512; p += 256){
    int gte = p & 15, gk = p >> 4;
    int t   = (te0 + gte) >> 12;
    int vid = s_mem[gte*32 + gk];
    const float4* src = reinterpret_cast<const float4*>(&np[((size_t)(t*VV) + vid)*16]);
    float4 f0 = src[0], f1 = src[1], f2 = src[2], f3 = src[3];
    uint4* dst = reinterpret_cast<uint4*>(&s_reg[(gk*16 + gte)*16]);
    dst[0] = pack8(f0, f1);
    dst[1] = pack8(f2, f3);
  }
  __syncthreads();
  int l = tid & 63;
  int w = tid >> 6;
  int lj = l & 15;
  int lg = l >> 4;
  float w0acc[4] = {0.f,0.f,0.f,0.f};
  float w1acc[4] = {0.f,0.f,0.f,0.f};
#pragma unroll
  for (int kk = 0; kk < 8; ++kk){
    int k = w*8 + kk;
    bf16x8 af = 0, b0 = 0, b1v = 0;
    if (l < 32){
      af  = *reinterpret_cast<const bf16x8*>(&s_reg[(k*16 + lj)*16 + lg*8]);
      b0  = *reinterpret_cast<const bf16x8*>(&twbf[((size_t)k*32 + lj)*16 + lg*8]);
      b1v = *reinterpret_cast<const bf16x8*>(&twbf[((size_t)k*32 + 16 + lj)*16 + lg*8]);
    }
    float tb0 = tb[k*32 + lj];
    float tb1 = tb[k*32 + 16 + lj];
    f32x4 c0 = {tb0, tb0, tb0, tb0};
    f32x4 c1 = {tb1, tb1, tb1, tb1};
    f32x4 s0 = __builtin_amdgcn_mfma_f32_16x16x32_bf16(af, b0,  c0, 0, 0, 0);
    f32x4 s1 = __builtin_amdgcn_mfma_f32_16x16x32_bf16(af, b1v, c1, 0, 0, 0);
    float cwk = cw[k];
#pragma unroll
    for (int i = 0; i < 4; ++i){
      float v0 = s0[i], v1 = s1[i];
      float m = fmaxf(v0, v1);
#pragma unroll
      for (int off = 1; off < 16; off <<= 1) m = fmaxf(m, __shfl_xor(m, off, 16));
      float e0 = expf(v0 - m), e1 = expf(v1 - m);
      float sm = e0 + e1;
#pragma unroll
      for (int off = 1; off < 16; off <<= 1) sm += __shfl_xor(sm, off, 16);
      float f = cwk / sm;
      w0acc[i] = fmaf(e0, f, w0acc[i]);
      w1acc[i] = fmaf(e1, f, w1acc[i]);
    }
  }
#pragma unroll
  for (int i = 0; i < 4; ++i){
    int ter = lg*4 + i;
    s_wsumP[w][ter][lj]      = w0acc[i];
    s_wsumP[w][ter][16 + lj] = w1acc[i];
  }
  __syncthreads();
  int te = tid >> 4, d = tid & 15;
  float he = cb[0];
#pragma unroll
  for (int j = 0; j < 32; ++j){
    float ws = s_wsumP[0][te][j] + s_wsumP[1][te][j]
             + s_wsumP[2][te][j] + s_wsumP[3][te][j];
    he = fmaf(ws, bf2f(s_reg[(j*16 + te)*16 + d]), he);
  }
  // fragment-major write: f16 = blockIdx.x, s=0, l = (d>>3)*16 + (te&15), e = d&7
  int f16 = blockIdx.x;
  Abf[((size_t)(f16*NSTEP + 0)*64 + (d >> 3)*16 + te)*8 + (d & 7)] = f2bf(he);
}

// ---------------------------------------------------------------------------
// K3: B-stationary bf16 MFMA GEMM, fragment-major A and B, XCD swizzle.
// bid = group*48 + nc*8 + mbr: all 6 n-chunks of an m-panel share bid%8.
// B chunk (3 n16-groups x 800k = 76.8 KB) LDS-resident; linear staging copy;
// one barrier; all LDS reads lane-consecutive (conflict-free); A loads 1KB
// contiguous per wave.
// ---------------------------------------------------------------------------
__global__ __launch_bounds__(256) void k3_gemm_mfma(
    const unsigned short* __restrict__ Abf,
    const unsigned short* __restrict__ Bbf, const float* __restrict__ b1,
    const float* __restrict__ w2, float* __restrict__ esc,
    float* __restrict__ C_pe){
  __shared__ unsigned short Bs[3*NSTEP*64*8];   // 76.8 KB
  int tid = threadIdx.x;
  int bid = blockIdx.x;
  int group = bid / 48;
  int within = bid - group*48;
  int nc  = within >> 3;        // 0..5
  int mbr = within & 7;
  int mb  = group*8 + mbr;      // 0..127
  {
    const uint4* src = reinterpret_cast<const uint4*>(&Bbf[(size_t)(nc*3)*NSTEP*64*8]);
    uint4* dst = reinterpret_cast<uint4*>(Bs);
    for (int i = tid; i < 4800; i += 256) dst[i] = src[i];
  }
  __syncthreads();
  int l = tid & 63, w = tid >> 6;
  int lr = l & 15, ls = l >> 4;
  int m0 = mb*128 + w*32;
  int f16 = (m0 >> 4);
  const unsigned short* a0p = &Abf[(size_t)f16*NSTEP*512];
  f32x4 acc[2][3] = {};
#pragma unroll
  for (int s = 0; s < NSTEP; ++s){
    bf16x8 af0 = *reinterpret_cast<const bf16x8*>(&a0p[(s*64 + l)*8]);
    bf16x8 af1 = *reinterpret_cast<const bf16x8*>(&a0p[((NSTEP + s)*64 + l)*8]);
#pragma unroll
    for (int j = 0; j < 3; ++j){
      bf16x8 bfv = *reinterpret_cast<const bf16x8*>(&Bs[((j*NSTEP + s)*64 + l)*8]);
      acc[0][j] = __builtin_amdgcn_mfma_f32_16x16x32_bf16(af0, bfv, acc[0][j], 0, 0, 0);
      acc[1][j] = __builtin_amdgcn_mfma_f32_16x16x32_bf16(af1, bfv, acc[1][j], 0, 0, 0);
    }
  }
  // epilogue
  float p[2][4] = {{0.f,0.f,0.f,0.f},{0.f,0.f,0.f,0.f}};
#pragma unroll
  for (int j = 0; j < 3; ++j){
    int n = nc*48 + j*16 + lr;
    bool hid = (n < NH);
    float b1n = hid ? b1[n] : 0.f;
    float w2n = hid ? w2[n] : 0.f;
#pragma unroll
    for (int i = 0; i < 2; ++i){
#pragma unroll
      for (int q = 0; q < 4; ++q){
        float v = acc[i][j][q];
        if (hid){
          p[i][q] += fmaxf(v + b1n, 0.f) * w2n;
        } else if (n < NTOT){
          int m = m0 + i*16 + ls*4 + q;
          C_pe[(size_t)m*64 + (n - NH)] = v;
        }
      }
    }
  }
  if (nc*48 < NH){
#pragma unroll
    for (int i = 0; i < 2; ++i){
#pragma unroll
      for (int q = 0; q < 4; ++q){
        float v = p[i][q];
#pragma unroll
        for (int off = 1; off < 16; off <<= 1) v += __shfl_xor(v, off, 16);
        if (lr == 0){
          int m = m0 + i*16 + ls*4 + q;
          atomicAdd(&esc[m], v);
        }
      }
    }
  }
}

// ---------------------------------------------------------------------------
// K456: fused edge-gather + LSTM2 + attention + FC. 16 lanes per vertex.
// ---------------------------------------------------------------------------
__global__ __launch_bounds__(256) void k456(
    const int* __restrict__ ve, const float* __restrict__ esc,
    const float* __restrict__ C_pe, const float* __restrict__ np,
    const float* __restrict__ Whh, const float* __restrict__ bih,
    const float* __restrict__ bhh,
    const float* __restrict__ ain, const float* __restrict__ aout,
    const float* __restrict__ fcw, const float* __restrict__ fcb,
    float* __restrict__ out){
  __shared__ float s_ain[16*17];
  __shared__ float s_aout[16*33];
  __shared__ float s_fc[32];
  __shared__ float s_fcb[2];
  int tid = threadIdx.x;
  { int j = tid >> 4, d = tid & 15; s_ain[j*17+d] = ain[tid]; }
  for (int i = tid; i < 512; i += 256){ int j = i >> 5, d = i & 31; s_aout[j*33+d] = aout[i]; }
  if (tid < 32) s_fc[tid] = fcw[tid];
  if (tid < 2)  s_fcb[tid] = fcb[tid];
  int lane = tid & 15;
  int v = (blockIdx.x*256 + tid) >> 4;
  float W[4][16], b[4];
#pragma unroll
  for (int gi=0; gi<4; ++gi){
    int j = gi*16 + lane;
    const float4* wr = reinterpret_cast<const float4*>(&Whh[j*16]);
    float4 w0=wr[0], w1=wr[1], w2=wr[2], w3=wr[3];
    W[gi][0]=w0.x; W[gi][1]=w0.y; W[gi][2]=w0.z; W[gi][3]=w0.w;
    W[gi][4]=w1.x; W[gi][5]=w1.y; W[gi][6]=w1.z; W[gi][7]=w1.w;
    W[gi][8]=w2.x; W[gi][9]=w2.y; W[gi][10]=w2.z; W[gi][11]=w2.w;
    W[gi][12]=w3.x; W[gi][13]=w3.y; W[gi][14]=w3.z; W[gi][15]=w3.w;
    b[gi] = bih[j] + bhh[j];
  }
  __syncthreads();
  float h = 0.f, c = 0.f;
  float la0, la1, la2, la3;
#pragma unroll
  for (int t=0; t<TT; ++t){
    const int* vp = &ve[((size_t)(t*VV) + v)*8];
    int e[8]; float wv[8];
    float mx = -1e30f;
#pragma unroll
    for (int d = 0; d < 8; ++d){
      e[d] = vp[d];
      wv[d] = esc[(t << 12) + e[d]];
      mx = fmaxf(mx, wv[d]);
    }
    float s = 0.f;
#pragma unroll
    for (int d = 0; d < 8; ++d){ wv[d] = expf(wv[d]-mx); s += wv[d]; }
    float inv = 1.f/s;
#pragma unroll
    for (int d = 0; d < 8; ++d) wv[d] *= inv;
    float g0 = b[0], g1 = b[1], g2 = b[2], g3 = b[3];
#pragma unroll
    for (int d = 0; d < 8; ++d){
      const float* cp = &C_pe[(size_t)((t << 12) + e[d])*64];
      g0 = fmaf(wv[d], cp[lane],      g0);
      g1 = fmaf(wv[d], cp[16 + lane], g1);
      g2 = fmaf(wv[d], cp[32 + lane], g2);
      g3 = fmaf(wv[d], cp[48 + lane], g3);
    }
#pragma unroll
    for (int d=0; d<16; ++d){
      float hb = __shfl(h, d, 16);
      g0 = fmaf(hb, W[0][d], g0);
      g1 = fmaf(hb, W[1][d], g1);
      g2 = fmaf(hb, W[2][d], g2);
      g3 = fmaf(hb, W[3][d], g3);
    }
    float ig = sigmoidf_(g0);
    float fg = sigmoidf_(g1);
    float gg = tanhf(g2);
    float og = sigmoidf_(g3);
    c = fmaf(fg, c, ig*gg);
    h = og * tanhf(c);
    float la = h + np[(size_t)(t*VV+v)*16 + lane];
    if (t == 0) la0 = la; else if (t == 1) la1 = la;
    else if (t == 2) la2 = la; else la3 = la;
  }
  float q = 0.f;
#pragma unroll
  for (int d=0; d<16; ++d){
    float bb = __shfl(la3, d, 16);
    q = fmaf(bb, s_ain[lane*17+d], q);
  }
  float aw0 = q*la0, aw1 = q*la1, aw2 = q*la2, aw3 = q*la3;
#pragma unroll
  for (int off=1; off<16; off<<=1){
    aw0 += __shfl_xor(aw0, off, 16);
    aw1 += __shfl_xor(aw1, off, 16);
    aw2 += __shfl_xor(aw2, off, 16);
    aw3 += __shfl_xor(aw3, off, 16);
  }
  float mx = fmaxf(fmaxf(aw0,aw1), fmaxf(aw2,aw3));
  aw0 = expf(aw0-mx); aw1 = expf(aw1-mx); aw2 = expf(aw2-mx); aw3 = expf(aw3-mx);
  float inv = 1.f/(aw0+aw1+aw2+aw3);
  float mix = (aw0*la0 + aw1*la1 + aw2*la2 + aw3*la3) * inv;
  float a = 0.f;
#pragma unroll
  for (int d=0; d<16; ++d){
    float m  = __shfl(mix, d, 16);
    float qq = __shfl(q,  d, 16);
    a = fmaf(m,  s_aout[lane*33+d],    a);
    a = fmaf(qq, s_aout[lane*33+16+d], a);
  }
  float at = tanhf(a);
  float p0 = at * s_fc[lane];
  float p1 = at * s_fc[16+lane];
#pragma unroll
  for (int off=1; off<16; off<<=1){
    p0 += __shfl_xor(p0, off, 16);
    p1 += __shfl_xor(p1, off, 16);
  }
  if (lane == 0){
    out[(size_t)v*2 + 0] = p0 + s_fcb[0];
    out[(size_t)v*2 + 1] = p1 + s_fcb[1];
  }
}

// ---------------------------------------------------------------------------
extern "C" void kernel_launch(void* const* d_in, const int* in_sizes, int n_in,
                              void* d_out, int out_size, void* d_ws, size_t ws_size,
                              hipStream_t stream){
  const float* prices = (const float*)d_in[0];
  const float* node   = (const float*)d_in[1];
  const int*   mem    = (const int*)d_in[2];
  const int*   ve     = (const int*)d_in[3];
  const float* Wih_p  = (const float*)d_in[4];
  const float* Whh_p  = (const float*)d_in[5];
  const float* bih_p  = (const float*)d_in[6];
  const float* bhh_p  = (const float*)d_in[7];
  const float* Wih_m  = (const float*)d_in[8];
  const float* Whh_m  = (const float*)d_in[9];
  const float* bih_m  = (const float*)d_in[10];
  const float* bhh_m  = (const float*)d_in[11];
  const float* tw     = (const float*)d_in[12];
  const float* tb     = (const float*)d_in[13];
  const float* cw     = (const float*)d_in[14];
  const float* cb     = (const float*)d_in[15];
  const float* w1     = (const float*)d_in[16];
  const float* b1     = (const float*)d_in[17];
  const float* w2     = (const float*)d_in[18];
  // d_in[19] = ec_b2: cancels in softmax, unused
  const float* ain    = (const float*)d_in[20];
  const float* aout   = (const float*)d_in[21];
  const float* fcw    = (const float*)d_in[22];
  const float* fcb    = (const float*)d_in[23];

  // workspace layout
  float* np_buf = (float*)d_ws;                       // T*V*16   = 262144 f
  float* esc    = np_buf + (size_t)TT*VV*HH;          // T*E      = 16384 f
  float* C_pe   = esc    + (size_t)TT*EE;             // 16384*64 = 1048576 f
  unsigned short* Bbf  = (unsigned short*)(C_pe + (size_t)TT*EE*64); // 18*25*512 u16
  unsigned short* twbf = Bbf + (size_t)18*NSTEP*512;                 // 1024*16 u16
  unsigned short* Abf  = twbf + (size_t)1024*16;                     // 1024*25*512 u16

  kP<<<1316, 256, 0, stream>>>(prices, Wih_p, Whh_p, bih_p, bhh_p, np_buf,
                               w1, Wih_m, Bbf, tw, twbf, esc, node, Abf);
  k2_fused<<<(TT*EE)/16, 256, 0, stream>>>(np_buf, mem, twbf, tb, cw, cb, Abf);
  k3_gemm_mfma<<<768, 256, 0, stream>>>(Abf, Bbf, b1, w2, esc, C_pe);
  k456<<<(VV*16)/256, 256, 0, stream>>>(ve, esc, C_pe, np_buf, Whh_m, bih_m, bhh_m,
                                        ain, aout, fcw, fcb, (float*)d_out);
}

// Round 9
// 197.155 us; speedup vs baseline: 5.0975x; 1.0449x over previous
//
#include <hip/hip_runtime.h>
#include <hip/hip_bf16.h>
#include <math.h>

// Problem constants
#define TT 4
#define VV 4096
#define EE 4096
#define KK 32
#define DD 8
#define HH 16
#define BERTD 768
#define CATD 784
#define NH 196      // CAT/4 hidden units of EdgeConv MLP
#define NTOT 260    // 196 hidden + 64 pe (Wih_m projection)
#define NSTEP 25    // K steps of 32 (K padded to 800)
#define NPB 288     // N padded to 18*16 (6 chunks x 48)

typedef __bf16 bf16x8 __attribute__((ext_vector_type(8)));
typedef float  f32x4  __attribute__((ext_vector_type(4)));

__device__ __forceinline__ float sigmoidf_(float x){ return 1.0f/(1.0f+expf(-x)); }
__device__ __forceinline__ unsigned short f2bf(float f){
  __bf16 h = (__bf16)f;
  return __builtin_bit_cast(unsigned short, h);
}
__device__ __forceinline__ float bf2f(unsigned short u){
  unsigned int x = ((unsigned int)u) << 16;
  return __builtin_bit_cast(float, x);
}
__device__ __forceinline__ uint4 pack8(float4 a, float4 b){
  uint4 u;
  u.x = (unsigned)f2bf(a.x) | ((unsigned)f2bf(a.y) << 16);
  u.y = (unsigned)f2bf(a.z) | ((unsigned)f2bf(a.w) << 16);
  u.z = (unsigned)f2bf(b.x) | ((unsigned)f2bf(b.y) << 16);
  u.w = (unsigned)f2bf(b.z) | ((unsigned)f2bf(b.w) << 16);
  return u;
}

// Fragment-major A layout: Abf[((f16*25 + s)*64 + l)*8 + e]
//   <-> A[row = f16*16 + (l&15)][k = s*32 + (l>>4)*8 + e]
// Fragment-major B layout: Bbf[((n16*25 + s)*64 + l)*8 + e]

// ---------------------------------------------------------------------------
// kP: fused prep.
//  blocks [0,1024):     pack node_embs -> Abf fragment-major (k>=16)
//  blocks [1024,1280):  price LSTM (16 lanes/vertex) -> np (T,V,16) f32
//  blocks [1280,1298):  pack [ec_w1 ; Wih_m] -> Bbf fragment-major
//  blocks [1298,1300):  pack vc_trans_w -> twbf[32*32][16] bf16
//  blocks [1300,1316):  zero esc (16384 f32)
// ---------------------------------------------------------------------------
__global__ __launch_bounds__(256) void kP(
    const float* __restrict__ prices,
    const float* __restrict__ Wih, const float* __restrict__ Whh,
    const float* __restrict__ bih, const float* __restrict__ bhh,
    float* __restrict__ np_out,
    const float* __restrict__ w1, const float* __restrict__ wm,
    unsigned short* __restrict__ Bbf,
    const float* __restrict__ tw, unsigned short* __restrict__ twbf,
    float* __restrict__ esc,
    const float* __restrict__ node, unsigned short* __restrict__ Abf){
  int b = blockIdx.x;
  int tid = threadIdx.x;
  if (b < 1024){
    int f16 = b;
    for (int i = tid; i < 1600; i += 256){
      int s = i >> 6, l = i & 63;
      int lr = l & 15, ls = l >> 4;
      int k = s*32 + ls*8;
      if (s == 0 && ls < 2) continue;            // k<16: he_emb, written by k2
      uint4* dst = reinterpret_cast<uint4*>(&Abf[((size_t)(f16*NSTEP + s)*64 + l)*8]);
      if (k >= CATD){
        uint4 z = {0,0,0,0};
        *dst = z;
      } else {
        int row = f16*16 + lr;
        const float* src = &node[(size_t)row*BERTD + (k - 16)];
        float4 f0 = *reinterpret_cast<const float4*>(&src[0]);
        float4 f1 = *reinterpret_cast<const float4*>(&src[4]);
        *dst = pack8(f0, f1);
      }
    }
  } else if (b < 1280){
    int bb2 = b - 1024;
    int lane = tid & 15;
    int v    = (bb2*256 + tid) >> 4;
    float W[4][16], wih[4], bb[4];
#pragma unroll
    for (int gi=0; gi<4; ++gi){
      int j = gi*16 + lane;
      const float4* wr = reinterpret_cast<const float4*>(&Whh[j*16]);
      float4 w0=wr[0], w1v=wr[1], w2v=wr[2], w3v=wr[3];
      W[gi][0]=w0.x; W[gi][1]=w0.y; W[gi][2]=w0.z; W[gi][3]=w0.w;
      W[gi][4]=w1v.x; W[gi][5]=w1v.y; W[gi][6]=w1v.z; W[gi][7]=w1v.w;
      W[gi][8]=w2v.x; W[gi][9]=w2v.y; W[gi][10]=w2v.z; W[gi][11]=w2v.w;
      W[gi][12]=w3v.x; W[gi][13]=w3v.y; W[gi][14]=w3v.z; W[gi][15]=w3v.w;
      wih[gi] = Wih[j];
      bb[gi]  = bih[j] + bhh[j];
    }
    float h = 0.f, c = 0.f;
    for (int t=0; t<TT; ++t){
      float x = prices[t*VV + v];
      float a0 = fmaf(x, wih[0], bb[0]);
      float a1 = fmaf(x, wih[1], bb[1]);
      float a2 = fmaf(x, wih[2], bb[2]);
      float a3 = fmaf(x, wih[3], bb[3]);
#pragma unroll
      for (int d=0; d<16; ++d){
        float hb = __shfl(h, d, 16);
        a0 = fmaf(hb, W[0][d], a0);
        a1 = fmaf(hb, W[1][d], a1);
        a2 = fmaf(hb, W[2][d], a2);
        a3 = fmaf(hb, W[3][d], a3);
      }
      float ig = sigmoidf_(a0);
      float fg = sigmoidf_(a1);
      float gg = tanhf(a2);
      float og = sigmoidf_(a3);
      c = fmaf(fg, c, ig*gg);
      h = og * tanhf(c);
      np_out[(size_t)(t*VV+v)*16 + lane] = h;
    }
  } else if (b < 1298){
    int n16 = b - 1280;
    for (int i = tid; i < 1600; i += 256){
      int s = i >> 6, l = i & 63;
      int lr = l & 15, ls = l >> 4;
      int n = n16*16 + lr;
      int k = s*32 + ls*8;
      uint4* dst = reinterpret_cast<uint4*>(&Bbf[((size_t)(n16*NSTEP + s)*64 + l)*8]);
      if (n < NTOT && k < CATD){
        const float* src = (n < NH) ? &w1[(size_t)n*CATD + k]
                                    : &wm[(size_t)(n-NH)*CATD + k];
        float4 f0 = *reinterpret_cast<const float4*>(&src[0]);
        float4 f1 = *reinterpret_cast<const float4*>(&src[4]);
        *dst = pack8(f0, f1);
      } else {
        uint4 z = {0,0,0,0};
        *dst = z;
      }
    }
  } else if (b < 1300){
    int base = (b - 1298) * 512;
#pragma unroll
    for (int rr = 0; rr < 2; ++rr){
      int r = base + tid*2 + rr;
      const float* s = &tw[(size_t)r*16];
#pragma unroll
      for (int d = 0; d < 16; ++d) twbf[(size_t)r*16 + d] = f2bf(s[d]);
    }
  } else {
    int idx = ((b - 1300)*256 + tid)*4;
    float4 z = make_float4(0.f,0.f,0.f,0.f);
    *reinterpret_cast<float4*>(&esc[idx]) = z;
  }
}

// ---------------------------------------------------------------------------
// K2: VertexConv via MFMA. Block = 16 hyperedges (te) = one f16 group.
// Writes he_emb bf16 into Abf fragment-major slots (s=0, k=0..15).
// ---------------------------------------------------------------------------
__global__ __launch_bounds__(256) void k2_fused(
    const float* __restrict__ np, const int* __restrict__ mem,
    const unsigned short* __restrict__ twbf, const float* __restrict__ tb,
    const float* __restrict__ cw, const float* __restrict__ cb,
    unsigned short* __restrict__ Abf){
  __shared__ unsigned short s_reg[32*16*16];  // [k][te][d] bf16, 16 KB
  __shared__ float s_wsumP[4][16][32];        // per-wave partial wsum, 8 KB
  __shared__ int   s_mem[512];
  int tid = threadIdx.x;
  int te0 = blockIdx.x * 16;
  for (int i = tid; i < 512; i += 256) s_mem[i] = mem[(size_t)te0*32 + i];
  __syncthreads();
  for (int p = tid; p < 512; p += 256){
    int gte = p & 15, gk = p >> 4;
    int t   = (te0 + gte) >> 12;
    int vid = s_mem[gte*32 + gk];
    const float4* src = reinterpret_cast<const float4*>(&np[((size_t)(t*VV) + vid)*16]);
    float4 f0 = src[0], f1 = src[1], f2 = src[2], f3 = src[3];
    uint4* dst = reinterpret_cast<uint4*>(&s_reg[(gk*16 + gte)*16]);
    dst[0] = pack8(f0, f1);
    dst[1] = pack8(f2, f3);
  }
  __syncthreads();
  int l = tid & 63;
  int w = tid >> 6;
  int lj = l & 15;
  int lg = l >> 4;
  float w0acc[4] = {0.f,0.f,0.f,0.f};
  float w1acc[4] = {0.f,0.f,0.f,0.f};
#pragma unroll
  for (int kk = 0; kk < 8; ++kk){
    int k = w*8 + kk;
    bf16x8 af = 0, b0 = 0, b1v = 0;
    if (l < 32){
      af  = *reinterpret_cast<const bf16x8*>(&s_reg[(k*16 + lj)*16 + lg*8]);
      b0  = *reinterpret_cast<const bf16x8*>(&twbf[((size_t)k*32 + lj)*16 + lg*8]);
      b1v = *reinterpret_cast<const bf16x8*>(&twbf[((size_t)k*32 + 16 + lj)*16 + lg*8]);
    }
    float tb0 = tb[k*32 + lj];
    float tb1 = tb[k*32 + 16 + lj];
    f32x4 c0 = {tb0, tb0, tb0, tb0};
    f32x4 c1 = {tb1, tb1, tb1, tb1};
    f32x4 s0 = __builtin_amdgcn_mfma_f32_16x16x32_bf16(af, b0,  c0, 0, 0, 0);
    f32x4 s1 = __builtin_amdgcn_mfma_f32_16x16x32_bf16(af, b1v, c1, 0, 0, 0);
    float cwk = cw[k];
#pragma unroll
    for (int i = 0; i < 4; ++i){
      float v0 = s0[i], v1 = s1[i];
      float m = fmaxf(v0, v1);
#pragma unroll
      for (int off = 1; off < 16; off <<= 1) m = fmaxf(m, __shfl_xor(m, off, 16));
      float e0 = expf(v0 - m), e1 = expf(v1 - m);
      float sm = e0 + e1;
#pragma unroll
      for (int off = 1; off < 16; off <<= 1) sm += __shfl_xor(sm, off, 16);
      float f = cwk / sm;
      w0acc[i] = fmaf(e0, f, w0acc[i]);
      w1acc[i] = fmaf(e1, f, w1acc[i]);
    }
  }
#pragma unroll
  for (int i = 0; i < 4; ++i){
    int ter = lg*4 + i;
    s_wsumP[w][ter][lj]      = w0acc[i];
    s_wsumP[w][ter][16 + lj] = w1acc[i];
  }
  __syncthreads();
  int te = tid >> 4, d = tid & 15;
  float he = cb[0];
#pragma unroll
  for (int j = 0; j < 32; ++j){
    float ws = s_wsumP[0][te][j] + s_wsumP[1][te][j]
             + s_wsumP[2][te][j] + s_wsumP[3][te][j];
    he = fmaf(ws, bf2f(s_reg[(j*16 + te)*16 + d]), he);
  }
  int f16 = blockIdx.x;
  Abf[((size_t)(f16*NSTEP + 0)*64 + (d >> 3)*16 + te)*8 + (d & 7)] = f2bf(he);
}

// ---------------------------------------------------------------------------
// K3: bf16 MFMA GEMM, fragment-major A and B, NO LDS (B is L2-resident),
// no barriers. XCD swizzle: bid = group*48 + nc*8 + mbr -> all 6 n-chunks of
// an m-panel share bid%8. Wave = 32 rows x 48 cols; fully unrolled K loop.
// ---------------------------------------------------------------------------
__global__ __launch_bounds__(256) void k3_gemm_mfma(
    const unsigned short* __restrict__ Abf,
    const unsigned short* __restrict__ Bbf, const float* __restrict__ b1,
    const float* __restrict__ w2, float* __restrict__ esc,
    float* __restrict__ C_pe){
  int tid = threadIdx.x;
  int bid = blockIdx.x;
  int group = bid / 48;
  int within = bid - group*48;
  int nc  = within >> 3;        // 0..5
  int mbr = within & 7;
  int mb  = group*8 + mbr;      // 0..127
  int l = tid & 63, w = tid >> 6;
  int lr = l & 15, ls = l >> 4;
  int m0 = mb*128 + w*32;
  int f16 = (m0 >> 4);
  const unsigned short* a0p = &Abf[(size_t)f16*NSTEP*512];
  const unsigned short* bp  = &Bbf[(size_t)(nc*3)*NSTEP*512];
  f32x4 acc[2][3] = {};
#pragma unroll
  for (int s = 0; s < NSTEP; ++s){
    bf16x8 af0 = *reinterpret_cast<const bf16x8*>(&a0p[(s*64 + l)*8]);
    bf16x8 af1 = *reinterpret_cast<const bf16x8*>(&a0p[((NSTEP + s)*64 + l)*8]);
#pragma unroll
    for (int j = 0; j < 3; ++j){
      bf16x8 bfv = *reinterpret_cast<const bf16x8*>(&bp[((size_t)(j*NSTEP + s)*64 + l)*8]);
      acc[0][j] = __builtin_amdgcn_mfma_f32_16x16x32_bf16(af0, bfv, acc[0][j], 0, 0, 0);
      acc[1][j] = __builtin_amdgcn_mfma_f32_16x16x32_bf16(af1, bfv, acc[1][j], 0, 0, 0);
    }
  }
  // epilogue
  float p[2][4] = {{0.f,0.f,0.f,0.f},{0.f,0.f,0.f,0.f}};
#pragma unroll
  for (int j = 0; j < 3; ++j){
    int n = nc*48 + j*16 + lr;
    bool hid = (n < NH);
    float b1n = hid ? b1[n] : 0.f;
    float w2n = hid ? w2[n] : 0.f;
#pragma unroll
    for (int i = 0; i < 2; ++i){
#pragma unroll
      for (int q = 0; q < 4; ++q){
        float v = acc[i][j][q];
        if (hid){
          p[i][q] += fmaxf(v + b1n, 0.f) * w2n;
        } else if (n < NTOT){
          int m = m0 + i*16 + ls*4 + q;
          C_pe[(size_t)m*64 + (n - NH)] = v;
        }
      }
    }
  }
  if (nc*48 < NH){
#pragma unroll
    for (int i = 0; i < 2; ++i){
#pragma unroll
      for (int q = 0; q < 4; ++q){
        float v = p[i][q];
#pragma unroll
        for (int off = 1; off < 16; off <<= 1) v += __shfl_xor(v, off, 16);
        if (lr == 0){
          int m = m0 + i*16 + ls*4 + q;
          atomicAdd(&esc[m], v);
        }
      }
    }
  }
}

// ---------------------------------------------------------------------------
// K456: fused edge-gather + LSTM2 + attention + FC. 32 lanes per vertex:
// the two 16-lane halves split the 8-edge gather/blend (4 each), combine via
// shfl_xor(16,32); recurrence+attention run duplicated in both halves.
// Two-phase: all t's gathers/blends first (latency overlap), then recurrence.
// ---------------------------------------------------------------------------
__global__ __launch_bounds__(256) void k456(
    const int* __restrict__ ve, const float* __restrict__ esc,
    const float* __restrict__ C_pe, const float* __restrict__ np,
    const float* __restrict__ Whh, const float* __restrict__ bih,
    const float* __restrict__ bhh,
    const float* __restrict__ ain, const float* __restrict__ aout,
    const float* __restrict__ fcw, const float* __restrict__ fcb,
    float* __restrict__ out){
  __shared__ float s_ain[16*17];
  __shared__ float s_aout[16*33];
  __shared__ float s_fc[32];
  __shared__ float s_fcb[2];
  int tid = threadIdx.x;
  { int j = tid >> 4, d = tid & 15; s_ain[j*17+d] = ain[tid]; }
  for (int i = tid; i < 512; i += 256){ int j = i >> 5, d = i & 31; s_aout[j*33+d] = aout[i]; }
  if (tid < 32) s_fc[tid] = fcw[tid];
  if (tid < 2)  s_fcb[tid] = fcb[tid];
  int lane = tid & 15;
  int half = (tid >> 4) & 1;
  int v = (blockIdx.x*256 + tid) >> 5;
  float W[4][16], b[4];
#pragma unroll
  for (int gi=0; gi<4; ++gi){
    int j = gi*16 + lane;
    const float4* wr = reinterpret_cast<const float4*>(&Whh[j*16]);
    float4 w0=wr[0], w1=wr[1], w2=wr[2], w3=wr[3];
    W[gi][0]=w0.x; W[gi][1]=w0.y; W[gi][2]=w0.z; W[gi][3]=w0.w;
    W[gi][4]=w1.x; W[gi][5]=w1.y; W[gi][6]=w1.z; W[gi][7]=w1.w;
    W[gi][8]=w2.x; W[gi][9]=w2.y; W[gi][10]=w2.z; W[gi][11]=w2.w;
    W[gi][12]=w3.x; W[gi][13]=w3.y; W[gi][14]=w3.z; W[gi][15]=w3.w;
    b[gi] = bih[j] + bhh[j];
  }
  __syncthreads();
  // phase 1: gather + blend, all t (each half handles 4 of the 8 edges)
  float g[4][4];
#pragma unroll
  for (int t=0; t<TT; ++t){
    const int* vp = &ve[((size_t)(t*VV) + v)*8 + half*4];
    int e[4]; float wv[4];
    float mx = -1e30f;
#pragma unroll
    for (int d = 0; d < 4; ++d){
      e[d] = vp[d];
      wv[d] = esc[(t << 12) + e[d]];
      mx = fmaxf(mx, wv[d]);
    }
    mx = fmaxf(mx, __shfl_xor(mx, 16, 32));
    float s = 0.f;
#pragma unroll
    for (int d = 0; d < 4; ++d){ wv[d] = expf(wv[d]-mx); s += wv[d]; }
    s += __shfl_xor(s, 16, 32);
    float inv = 1.f/s;
    float g0 = 0.f, g1 = 0.f, g2 = 0.f, g3 = 0.f;
#pragma unroll
    for (int d = 0; d < 4; ++d){
      const float* cp = &C_pe[(size_t)((t << 12) + e[d])*64];
      g0 = fmaf(wv[d], cp[lane],      g0);
      g1 = fmaf(wv[d], cp[16 + lane], g1);
      g2 = fmaf(wv[d], cp[32 + lane], g2);
      g3 = fmaf(wv[d], cp[48 + lane], g3);
    }
    g[t][0] = g0*inv; g[t][1] = g1*inv; g[t][2] = g2*inv; g[t][3] = g3*inv;
  }
  // combine halves
#pragma unroll
  for (int t=0; t<TT; ++t)
#pragma unroll
    for (int gi=0; gi<4; ++gi)
      g[t][gi] += __shfl_xor(g[t][gi], 16, 32);
  // phase 2: LSTM recurrence + residual (duplicated in both halves)
  float h = 0.f, c = 0.f;
  float la0, la1, la2, la3;
#pragma unroll
  for (int t=0; t<TT; ++t){
    float g0 = g[t][0] + b[0];
    float g1 = g[t][1] + b[1];
    float g2 = g[t][2] + b[2];
    float g3 = g[t][3] + b[3];
#pragma unroll
    for (int d=0; d<16; ++d){
      float hb = __shfl(h, d, 16);
      g0 = fmaf(hb, W[0][d], g0);
      g1 = fmaf(hb, W[1][d], g1);
      g2 = fmaf(hb, W[2][d], g2);
      g3 = fmaf(hb, W[3][d], g3);
    }
    float ig = sigmoidf_(g0);
    float fg = sigmoidf_(g1);
    float gg = tanhf(g2);
    float og = sigmoidf_(g3);
    c = fmaf(fg, c, ig*gg);
    h = og * tanhf(c);
    float la = h + np[(size_t)(t*VV+v)*16 + lane];
    if (t == 0) la0 = la; else if (t == 1) la1 = la;
    else if (t == 2) la2 = la; else la3 = la;
  }
  // attention
  float q = 0.f;
#pragma unroll
  for (int d=0; d<16; ++d){
    float bb = __shfl(la3, d, 16);
    q = fmaf(bb, s_ain[lane*17+d], q);
  }
  float aw0 = q*la0, aw1 = q*la1, aw2 = q*la2, aw3 = q*la3;
#pragma unroll
  for (int off=1; off<16; off<<=1){
    aw0 += __shfl_xor(aw0, off, 16);
    aw1 += __shfl_xor(aw1, off, 16);
    aw2 += __shfl_xor(aw2, off, 16);
    aw3 += __shfl_xor(aw3, off, 16);
  }
  float mx = fmaxf(fmaxf(aw0,aw1), fmaxf(aw2,aw3));
  aw0 = expf(aw0-mx); aw1 = expf(aw1-mx); aw2 = expf(aw2-mx); aw3 = expf(aw3-mx);
  float inv = 1.f/(aw0+aw1+aw2+aw3);
  float mix = (aw0*la0 + aw1*la1 + aw2*la2 + aw3*la3) * inv;
  float a = 0.f;
#pragma unroll
  for (int d=0; d<16; ++d){
    float m  = __shfl(mix, d, 16);
    float qq = __shfl(q,  d, 16);
    a = fmaf(m,  s_aout[lane*33+d],    a);
    a = fmaf(qq, s_aout[lane*33+16+d], a);
  }
  float at = tanhf(a);
  float p0 = at * s_fc[lane];
  float p1 = at * s_fc[16+lane];
#pragma unroll
  for (int off=1; off<16; off<<=1){
    p0 += __shfl_xor(p0, off, 16);
    p1 += __shfl_xor(p1, off, 16);
  }
  if ((tid & 31) == 0){
    out[(size_t)v*2 + 0] = p0 + s_fcb[0];
    out[(size_t)v*2 + 1] = p1 + s_fcb[1];
  }
}

// ---------------------------------------------------------------------------
extern "C" void kernel_launch(void* const* d_in, const int* in_sizes, int n_in,
                              void* d_out, int out_size, void* d_ws, size_t ws_size,
                              hipStream_t stream){
  const float* prices = (const float*)d_in[0];
  const float* node   = (const float*)d_in[1];
  const int*   mem    = (const int*)d_in[2];
  const int*   ve     = (const int*)d_in[3];
  const float* Wih_p  = (const float*)d_in[4];
  const float* Whh_p  = (const float*)d_in[5];
  const float* bih_p  = (const float*)d_in[6];
  const float* bhh_p  = (const float*)d_in[7];
  const float* Wih_m  = (const float*)d_in[8];
  const float* Whh_m  = (const float*)d_in[9];
  const float* bih_m  = (const float*)d_in[10];
  const float* bhh_m  = (const float*)d_in[11];
  const float* tw     = (const float*)d_in[12];
  const float* tb     = (const float*)d_in[13];
  const float* cw     = (const float*)d_in[14];
  const float* cb     = (const float*)d_in[15];
  const float* w1     = (const float*)d_in[16];
  const float* b1     = (const float*)d_in[17];
  const float* w2     = (const float*)d_in[18];
  // d_in[19] = ec_b2: cancels in softmax, unused
  const float* ain    = (const float*)d_in[20];
  const float* aout   = (const float*)d_in[21];
  const float* fcw    = (const float*)d_in[22];
  const float* fcb    = (const float*)d_in[23];

  // workspace layout
  float* np_buf = (float*)d_ws;                       // T*V*16   = 262144 f
  float* esc    = np_buf + (size_t)TT*VV*HH;          // T*E      = 16384 f
  float* C_pe   = esc    + (size_t)TT*EE;             // 16384*64 = 1048576 f
  unsigned short* Bbf  = (unsigned short*)(C_pe + (size_t)TT*EE*64); // 18*25*512 u16
  unsigned short* twbf = Bbf + (size_t)18*NSTEP*512;                 // 1024*16 u16
  unsigned short* Abf  = twbf + (size_t)1024*16;                     // 1024*25*512 u16

  kP<<<1316, 256, 0, stream>>>(prices, Wih_p, Whh_p, bih_p, bhh_p, np_buf,
                               w1, Wih_m, Bbf, tw, twbf, esc, node, Abf);
  k2_fused<<<(TT*EE)/16, 256, 0, stream>>>(np_buf, mem, twbf, tb, cw, cb, Abf);
  k3_gemm_mfma<<<768, 256, 0, stream>>>(Abf, Bbf, b1, w2, esc, C_pe);
  k456<<<(VV*32)/256, 256, 0, stream>>>(ve, esc, C_pe, np_buf, Whh_m, bih_m, bhh_m,
                                        ain, aout, fcw, fcb, (float*)d_out);
}